// Round 1
// baseline (865.403 us; speedup 1.0000x reference)
//
#include <hip/hip_runtime.h>
#include <cstdint>
#include <cstddef>

// Problem constants (fixed by reference)
constexpr int B_ = 8, N_ = 4096, C_ = 256, H_ = 4, D_ = 64, P_ = 64;
constexpr int OC_ = 4 * C_;      // 1024 qkvv channels
constexpr int M_  = B_ * N_;     // 32768 tokens

#define DEV_INLINE __device__ __forceinline__

DEV_INLINE float wave_max(float v) {
#pragma unroll
  for (int o = 32; o; o >>= 1) v = fmaxf(v, __shfl_xor(v, o));
  return v;
}
DEV_INLINE float wave_sum(float v) {
#pragma unroll
  for (int o = 32; o; o >>= 1) v += __shfl_xor(v, o);
  return v;
}

// ---------------------------------------------------------------------------
// Transpose W_E [P][N] -> WET [N][P] for coalesced n-major loads in k_pair.
__global__ __launch_bounds__(256) void k_wet(const float* __restrict__ WE,
                                             float* __restrict__ wet) {
  __shared__ float t_s[64][65];
  const int n0 = blockIdx.x * 64;
  const int t = threadIdx.x;
#pragma unroll
  for (int j = 0; j < 16; ++j) {
    int idx = t + j * 256;
    int p = idx >> 6, nl = idx & 63;
    t_s[p][nl] = WE[(size_t)p * N_ + n0 + nl];
  }
  __syncthreads();
#pragma unroll
  for (int j = 0; j < 16; ++j) {
    int idx = t + j * 256;
    int nl = idx >> 6, p = idx & 63;
    wet[(size_t)(n0 + nl) * P_ + p] = t_s[p][nl];
  }
}

// ---------------------------------------------------------------------------
// qkvv = x @ W_qkvv^T : [32768,256] x [1024,256]^T -> [32768,1024]
// 64x64 tile, K-chunks of 64, LDS stored k-major [k][m] (stride 68 -> b128
// reads are 2-way/free), 4x4 accum per thread.
__global__ __launch_bounds__(256) void k_qkvv(const float* __restrict__ x,
                                              const float* __restrict__ W,
                                              float* __restrict__ out) {
  __shared__ float As[64][68];
  __shared__ float Bs[64][68];
  const int t = threadIdx.x;
  const int bm = blockIdx.x * 64;
  const int bo = blockIdx.y * 64;
  const int lr = t >> 2;            // 0..63 row of the tile being loaded
  const int lq = (t & 3) << 4;      // 0,16,32,48 k-offset
  const int tm = (t & 15) << 2;     // output rows
  const int tn = (t >> 4) << 2;     // output cols
  float acc[4][4] = {};
  for (int k0 = 0; k0 < C_; k0 += 64) {
    float4 av[4], bv[4];
    const float* ap = x + (size_t)(bm + lr) * C_ + k0 + lq;
    const float* bp = W + (size_t)(bo + lr) * C_ + k0 + lq;
#pragma unroll
    for (int j = 0; j < 4; ++j) {
      av[j] = *(const float4*)(ap + 4 * j);
      bv[j] = *(const float4*)(bp + 4 * j);
    }
    __syncthreads();
#pragma unroll
    for (int j = 0; j < 4; ++j) {
      As[lq + 4 * j + 0][lr] = av[j].x; As[lq + 4 * j + 1][lr] = av[j].y;
      As[lq + 4 * j + 2][lr] = av[j].z; As[lq + 4 * j + 3][lr] = av[j].w;
      Bs[lq + 4 * j + 0][lr] = bv[j].x; Bs[lq + 4 * j + 1][lr] = bv[j].y;
      Bs[lq + 4 * j + 2][lr] = bv[j].z; Bs[lq + 4 * j + 3][lr] = bv[j].w;
    }
    __syncthreads();
#pragma unroll 8
    for (int kk = 0; kk < 64; ++kk) {
      const float4 a4 = *(const float4*)&As[kk][tm];
      const float4 b4 = *(const float4*)&Bs[kk][tn];
      const float a[4] = {a4.x, a4.y, a4.z, a4.w};
      const float b[4] = {b4.x, b4.y, b4.z, b4.w};
#pragma unroll
      for (int i = 0; i < 4; ++i)
#pragma unroll
        for (int j = 0; j < 4; ++j) acc[i][j] += a[i] * b[j];
    }
  }
#pragma unroll
  for (int i = 0; i < 4; ++i) {
    float4 v;
    v.x = acc[i][0]; v.y = acc[i][1]; v.z = acc[i][2]; v.w = acc[i][3];
    *(float4*)(out + (size_t)(bm + tm + i) * OC_ + bo + tn) = v;
  }
}

// ---------------------------------------------------------------------------
// Token-axis sum-of-squares for q (channels 0..255) and k (channels 256..511).
__global__ __launch_bounds__(256) void k_norms_partial(const float* __restrict__ qkvv,
                                                       float* __restrict__ ssq) {
  const int g = blockIdx.x;           // b*2 + half
  const int b = g >> 1, half = g & 1;
  const int n0 = blockIdx.y * 512;
  const int c = threadIdx.x;          // 0..255
  const float* p = qkvv + (size_t)b * N_ * OC_ + half * 256 + c;
  float ss = 0.f;
  for (int n = 0; n < 512; ++n) {
    float v = p[(size_t)(n0 + n) * OC_];
    ss += v * v;
  }
  atomicAdd(&ssq[(size_t)b * 512 + half * 256 + c], ss);
}

__global__ void k_norms_final(const float* __restrict__ ssq, float* __restrict__ rn) {
  const int i = blockIdx.x * 256 + threadIdx.x;  // 4096
  rn[i] = 1.f / fmaxf(sqrtf(ssq[i]), 1e-12f);
}

// ---------------------------------------------------------------------------
// Per-(b,h) contractions over tokens: op0 S_qk = q.k^T, op1 k_proj = k.WET,
// op2 v_proj = v_sa.WET. Split over 8 n-chunks, atomic accumulate.
__global__ __launch_bounds__(256) void k_pair(const float* __restrict__ qkvv,
                                              const float* __restrict__ wet,
                                              float* __restrict__ Sqk,
                                              float* __restrict__ kp,
                                              float* __restrict__ vp) {
  __shared__ float At[64][68];
  __shared__ float Bt[64][68];
  const int bh = blockIdx.x;  // 0..31
  const int op = blockIdx.y;  // 0..2
  const int nc = blockIdx.z;  // 0..7
  const int b = bh >> 2, h = bh & 3;
  const int t = threadIdx.x;
  const size_t qbase = (size_t)b * N_ * OC_;
  const float* Abase;
  const float* Bbase;
  size_t Bstride;
  float* out;
  if (op == 0) {
    Abase = qkvv + qbase + h * 64;
    Bbase = qkvv + qbase + 256 + h * 64; Bstride = OC_;
    out = Sqk;
  } else if (op == 1) {
    Abase = qkvv + qbase + 256 + h * 64;
    Bbase = wet; Bstride = P_;
    out = kp;
  } else {
    Abase = qkvv + qbase + 768 + h * 64;
    Bbase = wet; Bstride = P_;
    out = vp;
  }
  out += (size_t)bh * 64 * 64;
  const int ch = t & 63;
  const int nr = t >> 6;            // 0..3
  const int ta = (t & 15) << 2;
  const int tb = (t >> 4) << 2;
  float acc[4][4] = {};
  for (int s = 0; s < 8; ++s) {
    const int n0 = nc * 512 + s * 64;
    __syncthreads();
#pragma unroll
    for (int j = 0; j < 16; ++j) {
      int nl = nr + 4 * j;
      At[nl][ch] = Abase[(size_t)(n0 + nl) * OC_ + ch];
      Bt[nl][ch] = Bbase[(size_t)(n0 + nl) * Bstride + ch];
    }
    __syncthreads();
#pragma unroll 8
    for (int nn = 0; nn < 64; ++nn) {
      const float4 a4 = *(const float4*)&At[nn][ta];
      const float4 b4 = *(const float4*)&Bt[nn][tb];
      const float a[4] = {a4.x, a4.y, a4.z, a4.w};
      const float bb[4] = {b4.x, b4.y, b4.z, b4.w};
#pragma unroll
      for (int i = 0; i < 4; ++i)
#pragma unroll
        for (int j = 0; j < 4; ++j) acc[i][j] += a[i] * bb[j];
    }
  }
#pragma unroll
  for (int i = 0; i < 4; ++i)
#pragma unroll
    for (int j = 0; j < 4; ++j)
      atomicAdd(&out[(size_t)(ta + i) * 64 + tb + j], acc[i][j]);
}

// ---------------------------------------------------------------------------
// Channel-attn softmax: logits = S_qk * rq[dd] * rk[e] * temp[h], softmax over e.
__global__ __launch_bounds__(256) void k_ca_softmax(float* __restrict__ Sqk,
                                                    const float* __restrict__ rn,
                                                    const float* __restrict__ temp) {
  const int w = threadIdx.x >> 6;
  const int lane = threadIdx.x & 63;
  const int row = blockIdx.x * 4 + w;  // 0..2047 == b*256 + h*64 + dd
  const int b = row >> 8;
  const int rem = row & 255;
  const int h = rem >> 6;
  const float rq = rn[b * 512 + rem];
  const float rk = rn[b * 512 + 256 + h * 64 + lane];
  const float l = Sqk[(size_t)row * 64 + lane] * rq * rk * temp[h];
  const float m = wave_max(l);
  const float e = __expf(l - m);
  const float s = wave_sum(e);
  Sqk[(size_t)row * 64 + lane] = e / s;
}

// ---------------------------------------------------------------------------
// x_ca[b,n,h*64+dd] = sum_e attn_ca[b,h,dd,e] * v_ca[b,h,e,n]. Wave per token.
__global__ __launch_bounds__(256) void k_ca_apply(const float* __restrict__ qkvv,
                                                  const float* __restrict__ attn,
                                                  float* __restrict__ x_ca) {
  __shared__ float A_s[64][65];
  const int bh = blockIdx.x;
  const int b = bh >> 2, h = bh & 3;
  const int t = threadIdx.x;
#pragma unroll
  for (int j = 0; j < 16; ++j) {
    int idx = t + j * 256;
    A_s[idx >> 6][idx & 63] = attn[(size_t)bh * 4096 + idx];
  }
  __syncthreads();
  const int lane = t & 63, w = t >> 6;
  const size_t qb = (size_t)b * N_ * OC_ + 512 + h * 64;
  for (int i = 0; i < 64; ++i) {
    const int n = blockIdx.y * 256 + w * 64 + i;
    const float vv = qkvv[qb + (size_t)n * OC_ + lane];
    float acc = 0.f;
#pragma unroll
    for (int e = 0; e < 64; ++e) acc += __shfl(vv, e) * A_s[lane][e];
    x_ca[(size_t)(b * N_ + n) * C_ + h * 64 + lane] = acc;
  }
}

// ---------------------------------------------------------------------------
// Spatial attn fused per token: scores = qn . k_proj (rq,temp2,b_E folded into
// LDS copy), softmax over p, out = attn @ v_proj^T. Wave per token.
__global__ __launch_bounds__(256) void k_sa(const float* __restrict__ qkvv,
                                            const float* __restrict__ kp,
                                            const float* __restrict__ vp,
                                            const float* __restrict__ bE,
                                            const float* __restrict__ rn,
                                            const float* __restrict__ temp2,
                                            float* __restrict__ x_sa) {
  __shared__ float kp_s[64][65];
  __shared__ float vp_s[64][65];
  const int bh = blockIdx.x;
  const int b = bh >> 2, h = bh & 3;
  const int t = threadIdx.x;
  const float t2 = temp2[h];
#pragma unroll
  for (int j = 0; j < 16; ++j) {
    int idx = t + j * 256;
    int dd = idx >> 6, p = idx & 63;
    float be = bE[p];
    kp_s[dd][p] = (kp[(size_t)bh * 4096 + idx] + be) * rn[b * 512 + h * 64 + dd] * t2;
    vp_s[dd][p] = vp[(size_t)bh * 4096 + idx] + be;
  }
  __syncthreads();
  const int lane = t & 63, w = t >> 6;
  const size_t qb = (size_t)b * N_ * OC_ + h * 64;
  for (int i = 0; i < 16; ++i) {
    const int n = blockIdx.y * 64 + w * 16 + i;
    const float qv = qkvv[qb + (size_t)n * OC_ + lane];
    float sc = 0.f;
#pragma unroll
    for (int dd = 0; dd < 64; ++dd) sc += __shfl(qv, dd) * kp_s[dd][lane];
    const float m = wave_max(sc);
    const float e = __expf(sc - m);
    const float s = wave_sum(e);
    const float a = e / s;
    float acc = 0.f;
#pragma unroll
    for (int p = 0; p < 64; ++p) acc += __shfl(a, p) * vp_s[lane][p];
    x_sa[(size_t)(b * N_ + n) * C_ + h * 64 + lane] = acc;
  }
}

// ---------------------------------------------------------------------------
// Final: out[:, :128] = PReLU(x_sa @ W1^T + b1), out[:,128:] = PReLU(x_ca @ W2^T + b2)
__global__ __launch_bounds__(256) void k_out(const float* __restrict__ x_sa,
                                             const float* __restrict__ x_ca,
                                             const float* __restrict__ W1,
                                             const float* __restrict__ b1,
                                             const float* __restrict__ W2,
                                             const float* __restrict__ b2,
                                             const float* __restrict__ pa,
                                             float* __restrict__ out) {
  __shared__ float As[64][68];
  __shared__ float Bs[64][68];
  const int t = threadIdx.x;
  const int bm = blockIdx.x * 64;
  const int bo = blockIdx.y * 64;     // 0,64,128,192
  const int half = bo >> 7;
  const float* A = half ? x_ca : x_sa;
  const float* W = half ? W2 : W1;
  const float* bias = half ? b2 : b1;
  const int wrow = bo & 127;
  const int lr = t >> 2;
  const int lq = (t & 3) << 4;
  const int tm = (t & 15) << 2;
  const int tn = (t >> 4) << 2;
  float acc[4][4] = {};
  for (int k0 = 0; k0 < C_; k0 += 64) {
    float4 av[4], bv[4];
    const float* ap = A + (size_t)(bm + lr) * C_ + k0 + lq;
    const float* bp = W + (size_t)(wrow + lr) * C_ + k0 + lq;
#pragma unroll
    for (int j = 0; j < 4; ++j) {
      av[j] = *(const float4*)(ap + 4 * j);
      bv[j] = *(const float4*)(bp + 4 * j);
    }
    __syncthreads();
#pragma unroll
    for (int j = 0; j < 4; ++j) {
      As[lq + 4 * j + 0][lr] = av[j].x; As[lq + 4 * j + 1][lr] = av[j].y;
      As[lq + 4 * j + 2][lr] = av[j].z; As[lq + 4 * j + 3][lr] = av[j].w;
      Bs[lq + 4 * j + 0][lr] = bv[j].x; Bs[lq + 4 * j + 1][lr] = bv[j].y;
      Bs[lq + 4 * j + 2][lr] = bv[j].z; Bs[lq + 4 * j + 3][lr] = bv[j].w;
    }
    __syncthreads();
#pragma unroll 8
    for (int kk = 0; kk < 64; ++kk) {
      const float4 a4 = *(const float4*)&As[kk][tm];
      const float4 b4 = *(const float4*)&Bs[kk][tn];
      const float a[4] = {a4.x, a4.y, a4.z, a4.w};
      const float b[4] = {b4.x, b4.y, b4.z, b4.w};
#pragma unroll
      for (int i = 0; i < 4; ++i)
#pragma unroll
        for (int j = 0; j < 4; ++j) acc[i][j] += a[i] * b[j];
    }
  }
  const float slope = pa[0];
#pragma unroll
  for (int i = 0; i < 4; ++i) {
    float4 v;
    float* vo = (float*)&v;
#pragma unroll
    for (int j = 0; j < 4; ++j) {
      float val = acc[i][j] + bias[wrow + tn + j];
      vo[j] = val >= 0.f ? val : slope * val;
    }
    *(float4*)(out + (size_t)(bm + tm + i) * C_ + bo + tn) = v;
  }
}

// ---------------------------------------------------------------------------
extern "C" void kernel_launch(void* const* d_in, const int* in_sizes, int n_in,
                              void* d_out, int out_size, void* d_ws, size_t ws_size,
                              hipStream_t stream) {
  (void)in_sizes; (void)n_in; (void)out_size; (void)ws_size;
  const float* x  = (const float*)d_in[0];
  // d_in[1] = bank (unused by forward)
  const float* Wq = (const float*)d_in[2];
  const float* WE = (const float*)d_in[3];
  const float* bE = (const float*)d_in[4];
  const float* t1 = (const float*)d_in[5];
  const float* t2 = (const float*)d_in[6];
  const float* W1 = (const float*)d_in[7];
  const float* b1 = (const float*)d_in[8];
  const float* W2 = (const float*)d_in[9];
  const float* b2 = (const float*)d_in[10];
  const float* pa = (const float*)d_in[11];
  float* out = (float*)d_out;

  float* ws = (float*)d_ws;
  size_t off = 0;
  float* qkvv = ws + off; off += (size_t)M_ * OC_;      // 33,554,432
  float* xsa  = ws + off; off += (size_t)M_ * C_;       //  8,388,608
  float* xca  = ws + off; off += (size_t)M_ * C_;       //  8,388,608
  float* wet  = ws + off; off += (size_t)N_ * P_;       //    262,144
  float* Sqk  = ws + off; off += (size_t)B_ * H_ * D_ * D_;  // 131,072
  float* kp   = ws + off; off += (size_t)B_ * H_ * D_ * P_;  // 131,072
  float* vp   = ws + off; off += (size_t)B_ * H_ * D_ * P_;  // 131,072
  float* ssq  = ws + off; off += (size_t)B_ * 512;      //      4,096
  float* rn   = ws + off; off += (size_t)B_ * 512;      //      4,096

  // Zero the atomically-accumulated buffers (Sqk,kp,vp,ssq are contiguous).
  hipMemsetAsync(Sqk, 0, (size_t)(3 * 131072 + 4096) * sizeof(float), stream);

  k_wet<<<64, 256, 0, stream>>>(WE, wet);
  k_qkvv<<<dim3(M_ / 64, OC_ / 64), 256, 0, stream>>>(x, Wq, qkvv);
  k_norms_partial<<<dim3(16, 8), 256, 0, stream>>>(qkvv, ssq);
  k_norms_final<<<16, 256, 0, stream>>>(ssq, rn);
  k_pair<<<dim3(32, 3, 8), 256, 0, stream>>>(qkvv, wet, Sqk, kp, vp);
  k_ca_softmax<<<512, 256, 0, stream>>>(Sqk, rn, t1);
  k_ca_apply<<<dim3(32, 16), 256, 0, stream>>>(qkvv, Sqk, xca);
  k_sa<<<dim3(32, 64), 256, 0, stream>>>(qkvv, kp, vp, bE, rn, t2, xsa);
  k_out<<<dim3(M_ / 64, 4), 256, 0, stream>>>(xsa, xca, W1, b1, W2, b2, pa, out);
}

// Round 2
// 598.721 us; speedup vs baseline: 1.4454x; 1.4454x over previous
//
#include <hip/hip_runtime.h>
#include <cstdint>
#include <cstddef>

// Problem constants (fixed by reference)
constexpr int B_ = 8, N_ = 4096, C_ = 256, H_ = 4, D_ = 64, P_ = 64;
constexpr int OC_ = 4 * C_;      // 1024 qkvv channels
constexpr int M_  = B_ * N_;     // 32768 tokens

#define DEV_INLINE __device__ __forceinline__

// ---------------------------------------------------------------------------
// Transpose W_E [P][N] -> WET [N][P] for coalesced n-major loads in k_pair.
__global__ __launch_bounds__(256) void k_wet(const float* __restrict__ WE,
                                             float* __restrict__ wet) {
  __shared__ float t_s[64][65];
  const int n0 = blockIdx.x * 64;
  const int t = threadIdx.x;
#pragma unroll
  for (int j = 0; j < 16; ++j) {
    int idx = t + j * 256;
    int p = idx >> 6, nl = idx & 63;
    t_s[p][nl] = WE[(size_t)p * N_ + n0 + nl];
  }
  __syncthreads();
#pragma unroll
  for (int j = 0; j < 16; ++j) {
    int idx = t + j * 256;
    int nl = idx >> 6, p = idx & 63;
    wet[(size_t)(n0 + nl) * P_ + p] = t_s[p][nl];
  }
}

// ---------------------------------------------------------------------------
// qkvv = x @ W_qkvv^T : [32768,256] x [1024,256]^T -> [32768,1024]
// 64x64 tile, K-chunks of 64, LDS stored k-major [k][m] (stride 68), 4x4 acc.
__global__ __launch_bounds__(256) void k_qkvv(const float* __restrict__ x,
                                              const float* __restrict__ W,
                                              float* __restrict__ out) {
  __shared__ float As[64][68];
  __shared__ float Bs[64][68];
  const int t = threadIdx.x;
  const int bm = blockIdx.x * 64;
  const int bo = blockIdx.y * 64;
  const int lr = t >> 2;            // 0..63 row of the tile being loaded
  const int lq = (t & 3) << 4;      // 0,16,32,48 k-offset
  const int tm = (t & 15) << 2;     // output rows
  const int tn = (t >> 4) << 2;     // output cols
  float acc[4][4] = {};
  for (int k0 = 0; k0 < C_; k0 += 64) {
    float4 av[4], bv[4];
    const float* ap = x + (size_t)(bm + lr) * C_ + k0 + lq;
    const float* bp = W + (size_t)(bo + lr) * C_ + k0 + lq;
#pragma unroll
    for (int j = 0; j < 4; ++j) {
      av[j] = *(const float4*)(ap + 4 * j);
      bv[j] = *(const float4*)(bp + 4 * j);
    }
    __syncthreads();
#pragma unroll
    for (int j = 0; j < 4; ++j) {
      As[lq + 4 * j + 0][lr] = av[j].x; As[lq + 4 * j + 1][lr] = av[j].y;
      As[lq + 4 * j + 2][lr] = av[j].z; As[lq + 4 * j + 3][lr] = av[j].w;
      Bs[lq + 4 * j + 0][lr] = bv[j].x; Bs[lq + 4 * j + 1][lr] = bv[j].y;
      Bs[lq + 4 * j + 2][lr] = bv[j].z; Bs[lq + 4 * j + 3][lr] = bv[j].w;
    }
    __syncthreads();
#pragma unroll 8
    for (int kk = 0; kk < 64; ++kk) {
      const float4 a4 = *(const float4*)&As[kk][tm];
      const float4 b4 = *(const float4*)&Bs[kk][tn];
      const float a[4] = {a4.x, a4.y, a4.z, a4.w};
      const float b[4] = {b4.x, b4.y, b4.z, b4.w};
#pragma unroll
      for (int i = 0; i < 4; ++i)
#pragma unroll
        for (int j = 0; j < 4; ++j) acc[i][j] += a[i] * b[j];
    }
  }
#pragma unroll
  for (int i = 0; i < 4; ++i) {
    float4 v;
    v.x = acc[i][0]; v.y = acc[i][1]; v.z = acc[i][2]; v.w = acc[i][3];
    *(float4*)(out + (size_t)(bm + tm + i) * OC_ + bo + tn) = v;
  }
}

// ---------------------------------------------------------------------------
// Token-axis sum-of-squares for q (channels 0..255) and k (channels 256..511).
__global__ __launch_bounds__(256) void k_norms_partial(const float* __restrict__ qkvv,
                                                       float* __restrict__ ssq) {
  const int g = blockIdx.x;           // b*2 + half
  const int b = g >> 1, half = g & 1;
  const int n0 = blockIdx.y * 512;
  const int c = threadIdx.x;          // 0..255
  const float* p = qkvv + (size_t)b * N_ * OC_ + half * 256 + c;
  float ss = 0.f;
  for (int n = 0; n < 512; ++n) {
    float v = p[(size_t)(n0 + n) * OC_];
    ss += v * v;
  }
  atomicAdd(&ssq[(size_t)b * 512 + half * 256 + c], ss);
}

__global__ void k_norms_final(const float* __restrict__ ssq, float* __restrict__ rn) {
  const int i = blockIdx.x * 256 + threadIdx.x;  // 4096
  rn[i] = 1.f / fmaxf(sqrtf(ssq[i]), 1e-12f);
}

// ---------------------------------------------------------------------------
// Per-(b,h) contractions over tokens: op0 S_qk = q.k^T ([d][e]),
// op1 k_proj = k.WET stored TRANSPOSED as [p][d], op2 v_proj = v_sa.WET [d][p].
__global__ __launch_bounds__(256) void k_pair(const float* __restrict__ qkvv,
                                              const float* __restrict__ wet,
                                              float* __restrict__ Sqk,
                                              float* __restrict__ kp,
                                              float* __restrict__ vp) {
  __shared__ float At[64][68];
  __shared__ float Bt[64][68];
  const int bh = blockIdx.x;  // 0..31
  const int op = blockIdx.y;  // 0..2
  const int nc = blockIdx.z;  // 0..7
  const int b = bh >> 2, h = bh & 3;
  const int t = threadIdx.x;
  const size_t qbase = (size_t)b * N_ * OC_;
  const float* Abase;
  const float* Bbase;
  size_t Bstride;
  float* out;
  if (op == 0) {
    Abase = qkvv + qbase + h * 64;
    Bbase = qkvv + qbase + 256 + h * 64; Bstride = OC_;
    out = Sqk;
  } else if (op == 1) {
    Abase = qkvv + qbase + 256 + h * 64;
    Bbase = wet; Bstride = P_;
    out = kp;
  } else {
    Abase = qkvv + qbase + 768 + h * 64;
    Bbase = wet; Bstride = P_;
    out = vp;
  }
  out += (size_t)bh * 64 * 64;
  const int ch = t & 63;
  const int nr = t >> 6;            // 0..3
  const int ta = (t & 15) << 2;
  const int tb = (t >> 4) << 2;
  float acc[4][4] = {};
  for (int s = 0; s < 8; ++s) {
    const int n0 = nc * 512 + s * 64;
    __syncthreads();
#pragma unroll
    for (int j = 0; j < 16; ++j) {
      int nl = nr + 4 * j;
      At[nl][ch] = Abase[(size_t)(n0 + nl) * OC_ + ch];
      Bt[nl][ch] = Bbase[(size_t)(n0 + nl) * Bstride + ch];
    }
    __syncthreads();
#pragma unroll 8
    for (int nn = 0; nn < 64; ++nn) {
      const float4 a4 = *(const float4*)&At[nn][ta];
      const float4 b4 = *(const float4*)&Bt[nn][tb];
      const float a[4] = {a4.x, a4.y, a4.z, a4.w};
      const float bb[4] = {b4.x, b4.y, b4.z, b4.w};
#pragma unroll
      for (int i = 0; i < 4; ++i)
#pragma unroll
        for (int j = 0; j < 4; ++j) acc[i][j] += a[i] * bb[j];
    }
  }
  if (op == 1) {
#pragma unroll
    for (int i = 0; i < 4; ++i)
#pragma unroll
      for (int j = 0; j < 4; ++j)
        atomicAdd(&out[(size_t)(tb + j) * 64 + ta + i], acc[i][j]);  // [p][d]
  } else {
#pragma unroll
    for (int i = 0; i < 4; ++i)
#pragma unroll
      for (int j = 0; j < 4; ++j)
        atomicAdd(&out[(size_t)(ta + i) * 64 + tb + j], acc[i][j]);
  }
}

// ---------------------------------------------------------------------------
// Channel-attn softmax: logits = S_qk * rq[dd] * rk[e] * temp[h], softmax over e.
__global__ __launch_bounds__(256) void k_ca_softmax(float* __restrict__ Sqk,
                                                    const float* __restrict__ rn,
                                                    const float* __restrict__ temp) {
  const int w = threadIdx.x >> 6;
  const int lane = threadIdx.x & 63;
  const int row = blockIdx.x * 4 + w;  // 0..2047 == b*256 + h*64 + dd
  const int b = row >> 8;
  const int rem = row & 255;
  const int h = rem >> 6;
  const float rq = rn[b * 512 + rem];
  const float rk = rn[b * 512 + 256 + h * 64 + lane];
  float l = Sqk[(size_t)row * 64 + lane] * rq * rk * temp[h];
  float m = l;
#pragma unroll
  for (int o = 32; o; o >>= 1) m = fmaxf(m, __shfl_xor(m, o));
  const float e = __expf(l - m);
  float s = e;
#pragma unroll
  for (int o = 32; o; o >>= 1) s += __shfl_xor(s, o);
  Sqk[(size_t)row * 64 + lane] = e / s;
}

// ---------------------------------------------------------------------------
// x_ca[b,n,h*64+d] = sum_e attn[b,h,d,e] * qkvv[n][512+h*64+e].
// 64-token tile; LDS-tiled 4x4 register GEMM (rows strided by 16 -> 2-way free).
__global__ __launch_bounds__(256) void k_ca_apply(const float* __restrict__ qkvv,
                                                  const float* __restrict__ attn,
                                                  float* __restrict__ x_ca) {
  __shared__ float Vs[64][68];   // [tok][e]
  __shared__ float As[64][68];   // [d][e]
  const int bh = blockIdx.x;
  const int b = bh >> 2, h = bh & 3;
  const int n0 = blockIdx.y * 64;
  const int t = threadIdx.x;
#pragma unroll
  for (int j = 0; j < 4; ++j) {
    int i4 = t + j * 256;          // float4 index 0..1023
    int row = i4 >> 4;
    int c0 = (i4 & 15) << 2;
    *(float4*)&As[row][c0] = *(const float4*)&attn[(size_t)bh * 4096 + (size_t)i4 * 4];
    *(float4*)&Vs[row][c0] =
        *(const float4*)&qkvv[(size_t)(b * N_ + n0 + row) * OC_ + 512 + h * 64 + c0];
  }
  __syncthreads();
  const int tm = t & 15;           // token rows tm+16*i
  const int tn = (t >> 4) << 2;    // channel cols
  float acc[4][4] = {};
#pragma unroll
  for (int e0 = 0; e0 < 64; e0 += 4) {
    float4 a4[4], b4[4];
#pragma unroll
    for (int i = 0; i < 4; ++i) a4[i] = *(const float4*)&Vs[tm + 16 * i][e0];
#pragma unroll
    for (int j = 0; j < 4; ++j) b4[j] = *(const float4*)&As[tn + j][e0];
#pragma unroll
    for (int i = 0; i < 4; ++i)
#pragma unroll
      for (int j = 0; j < 4; ++j)
        acc[i][j] += a4[i].x * b4[j].x + a4[i].y * b4[j].y +
                     a4[i].z * b4[j].z + a4[i].w * b4[j].w;
  }
#pragma unroll
  for (int i = 0; i < 4; ++i) {
    float4 v;
    v.x = acc[i][0]; v.y = acc[i][1]; v.z = acc[i][2]; v.w = acc[i][3];
    *(float4*)&x_ca[(size_t)(b * N_ + n0 + tm + 16 * i) * C_ + h * 64 + tn] = v;
  }
}

// ---------------------------------------------------------------------------
// Spatial attention, tiled: per (bh, 64-token tile):
//   S[tok][p] = sum_d Q[tok][d] * Ks[p][d]   (rq, t2, bE folded into Ks)
//   softmax rows of S over p
//   O[tok][d] = sum_p S[tok][p] * Vs[d][p]   (bE folded into Vs)
// kpT comes in [p][d]; vp comes in [d][p].
__global__ __launch_bounds__(256) void k_sa(const float* __restrict__ qkvv,
                                            const float* __restrict__ kpT,
                                            const float* __restrict__ vp,
                                            const float* __restrict__ bE,
                                            const float* __restrict__ rn,
                                            const float* __restrict__ temp2,
                                            float* __restrict__ x_sa) {
  __shared__ float Qs[64][68];   // [tok][d]; re-used as S [tok][p] after GEMM1
  __shared__ float Ks[64][68];   // [p][d] scaled
  __shared__ float Vs[64][68];   // [d][p] + bE
  const int bh = blockIdx.x;
  const int b = bh >> 2, h = bh & 3;
  const int n0 = blockIdx.y * 64;
  const int t = threadIdx.x;
  const float t2 = temp2[h];
#pragma unroll
  for (int j = 0; j < 4; ++j) {
    int i4 = t + j * 256;
    int row = i4 >> 4;             // p for Ks, d for Vs, tok for Qs
    int c0 = (i4 & 15) << 2;
    float4 kv = *(const float4*)&kpT[(size_t)bh * 4096 + (size_t)i4 * 4];
    float4 vv = *(const float4*)&vp[(size_t)bh * 4096 + (size_t)i4 * 4];
    const float be_r = bE[row];
    Ks[row][c0 + 0] = (kv.x + be_r) * rn[b * 512 + h * 64 + c0 + 0] * t2;
    Ks[row][c0 + 1] = (kv.y + be_r) * rn[b * 512 + h * 64 + c0 + 1] * t2;
    Ks[row][c0 + 2] = (kv.z + be_r) * rn[b * 512 + h * 64 + c0 + 2] * t2;
    Ks[row][c0 + 3] = (kv.w + be_r) * rn[b * 512 + h * 64 + c0 + 3] * t2;
    Vs[row][c0 + 0] = vv.x + bE[c0 + 0];
    Vs[row][c0 + 1] = vv.y + bE[c0 + 1];
    Vs[row][c0 + 2] = vv.z + bE[c0 + 2];
    Vs[row][c0 + 3] = vv.w + bE[c0 + 3];
    *(float4*)&Qs[row][c0] =
        *(const float4*)&qkvv[(size_t)(b * N_ + n0 + row) * OC_ + h * 64 + c0];
  }
  __syncthreads();
  const int tm = t & 15;           // token rows tm+16*i
  const int tn = (t >> 4) << 2;    // output cols (p in GEMM1, d in GEMM2)
  float acc[4][4] = {};
#pragma unroll
  for (int d0 = 0; d0 < 64; d0 += 4) {
    float4 a4[4], b4[4];
#pragma unroll
    for (int i = 0; i < 4; ++i) a4[i] = *(const float4*)&Qs[tm + 16 * i][d0];
#pragma unroll
    for (int j = 0; j < 4; ++j) b4[j] = *(const float4*)&Ks[tn + j][d0];
#pragma unroll
    for (int i = 0; i < 4; ++i)
#pragma unroll
      for (int j = 0; j < 4; ++j)
        acc[i][j] += a4[i].x * b4[j].x + a4[i].y * b4[j].y +
                     a4[i].z * b4[j].z + a4[i].w * b4[j].w;
  }
  __syncthreads();                 // all Qs reads done; safe to alias
  float(*Ss)[68] = Qs;
#pragma unroll
  for (int i = 0; i < 4; ++i) {
    float4 v;
    v.x = acc[i][0]; v.y = acc[i][1]; v.z = acc[i][2]; v.w = acc[i][3];
    *(float4*)&Ss[tm + 16 * i][tn] = v;
  }
  __syncthreads();
  // softmax: 4 threads per row, 16 elems each
  {
    const int r = t >> 2;
    const int s0 = (t & 3) << 4;
    float4 v0 = *(float4*)&Ss[r][s0 + 0];
    float4 v1 = *(float4*)&Ss[r][s0 + 4];
    float4 v2 = *(float4*)&Ss[r][s0 + 8];
    float4 v3 = *(float4*)&Ss[r][s0 + 12];
    float m = fmaxf(fmaxf(fmaxf(v0.x, v0.y), fmaxf(v0.z, v0.w)),
                    fmaxf(fmaxf(v1.x, v1.y), fmaxf(v1.z, v1.w)));
    m = fmaxf(m, fmaxf(fmaxf(fmaxf(v2.x, v2.y), fmaxf(v2.z, v2.w)),
                       fmaxf(fmaxf(v3.x, v3.y), fmaxf(v3.z, v3.w))));
    m = fmaxf(m, __shfl_xor(m, 1));
    m = fmaxf(m, __shfl_xor(m, 2));
    v0.x = __expf(v0.x - m); v0.y = __expf(v0.y - m);
    v0.z = __expf(v0.z - m); v0.w = __expf(v0.w - m);
    v1.x = __expf(v1.x - m); v1.y = __expf(v1.y - m);
    v1.z = __expf(v1.z - m); v1.w = __expf(v1.w - m);
    v2.x = __expf(v2.x - m); v2.y = __expf(v2.y - m);
    v2.z = __expf(v2.z - m); v2.w = __expf(v2.w - m);
    v3.x = __expf(v3.x - m); v3.y = __expf(v3.y - m);
    v3.z = __expf(v3.z - m); v3.w = __expf(v3.w - m);
    float s = (v0.x + v0.y + v0.z + v0.w) + (v1.x + v1.y + v1.z + v1.w) +
              (v2.x + v2.y + v2.z + v2.w) + (v3.x + v3.y + v3.z + v3.w);
    s += __shfl_xor(s, 1);
    s += __shfl_xor(s, 2);
    const float inv = 1.f / s;
    v0.x *= inv; v0.y *= inv; v0.z *= inv; v0.w *= inv;
    v1.x *= inv; v1.y *= inv; v1.z *= inv; v1.w *= inv;
    v2.x *= inv; v2.y *= inv; v2.z *= inv; v2.w *= inv;
    v3.x *= inv; v3.y *= inv; v3.z *= inv; v3.w *= inv;
    *(float4*)&Ss[r][s0 + 0] = v0;
    *(float4*)&Ss[r][s0 + 4] = v1;
    *(float4*)&Ss[r][s0 + 8] = v2;
    *(float4*)&Ss[r][s0 + 12] = v3;
  }
  __syncthreads();
  float acc2[4][4] = {};
#pragma unroll
  for (int p0 = 0; p0 < 64; p0 += 4) {
    float4 a4[4], b4[4];
#pragma unroll
    for (int i = 0; i < 4; ++i) a4[i] = *(const float4*)&Ss[tm + 16 * i][p0];
#pragma unroll
    for (int j = 0; j < 4; ++j) b4[j] = *(const float4*)&Vs[tn + j][p0];
#pragma unroll
    for (int i = 0; i < 4; ++i)
#pragma unroll
      for (int j = 0; j < 4; ++j)
        acc2[i][j] += a4[i].x * b4[j].x + a4[i].y * b4[j].y +
                      a4[i].z * b4[j].z + a4[i].w * b4[j].w;
  }
#pragma unroll
  for (int i = 0; i < 4; ++i) {
    float4 v;
    v.x = acc2[i][0]; v.y = acc2[i][1]; v.z = acc2[i][2]; v.w = acc2[i][3];
    *(float4*)&x_sa[(size_t)(b * N_ + n0 + tm + 16 * i) * C_ + h * 64 + tn] = v;
  }
}

// ---------------------------------------------------------------------------
// Final: out[:, :128] = PReLU(x_sa @ W1^T + b1), out[:,128:] = PReLU(x_ca @ W2^T + b2)
__global__ __launch_bounds__(256) void k_out(const float* __restrict__ x_sa,
                                             const float* __restrict__ x_ca,
                                             const float* __restrict__ W1,
                                             const float* __restrict__ b1,
                                             const float* __restrict__ W2,
                                             const float* __restrict__ b2,
                                             const float* __restrict__ pa,
                                             float* __restrict__ out) {
  __shared__ float As[64][68];
  __shared__ float Bs[64][68];
  const int t = threadIdx.x;
  const int bm = blockIdx.x * 64;
  const int bo = blockIdx.y * 64;     // 0,64,128,192
  const int half = bo >> 7;
  const float* A = half ? x_ca : x_sa;
  const float* W = half ? W2 : W1;
  const float* bias = half ? b2 : b1;
  const int wrow = bo & 127;
  const int lr = t >> 2;
  const int lq = (t & 3) << 4;
  const int tm = (t & 15) << 2;
  const int tn = (t >> 4) << 2;
  float acc[4][4] = {};
  for (int k0 = 0; k0 < C_; k0 += 64) {
    float4 av[4], bv[4];
    const float* ap = A + (size_t)(bm + lr) * C_ + k0 + lq;
    const float* bp = W + (size_t)(wrow + lr) * C_ + k0 + lq;
#pragma unroll
    for (int j = 0; j < 4; ++j) {
      av[j] = *(const float4*)(ap + 4 * j);
      bv[j] = *(const float4*)(bp + 4 * j);
    }
    __syncthreads();
#pragma unroll
    for (int j = 0; j < 4; ++j) {
      As[lq + 4 * j + 0][lr] = av[j].x; As[lq + 4 * j + 1][lr] = av[j].y;
      As[lq + 4 * j + 2][lr] = av[j].z; As[lq + 4 * j + 3][lr] = av[j].w;
      Bs[lq + 4 * j + 0][lr] = bv[j].x; Bs[lq + 4 * j + 1][lr] = bv[j].y;
      Bs[lq + 4 * j + 2][lr] = bv[j].z; Bs[lq + 4 * j + 3][lr] = bv[j].w;
    }
    __syncthreads();
#pragma unroll 8
    for (int kk = 0; kk < 64; ++kk) {
      const float4 a4 = *(const float4*)&As[kk][tm];
      const float4 b4 = *(const float4*)&Bs[kk][tn];
      const float a[4] = {a4.x, a4.y, a4.z, a4.w};
      const float b[4] = {b4.x, b4.y, b4.z, b4.w};
#pragma unroll
      for (int i = 0; i < 4; ++i)
#pragma unroll
        for (int j = 0; j < 4; ++j) acc[i][j] += a[i] * b[j];
    }
  }
  const float slope = pa[0];
#pragma unroll
  for (int i = 0; i < 4; ++i) {
    float4 v;
    float* vo = (float*)&v;
#pragma unroll
    for (int j = 0; j < 4; ++j) {
      float val = acc[i][j] + bias[wrow + tn + j];
      vo[j] = val >= 0.f ? val : slope * val;
    }
    *(float4*)(out + (size_t)(bm + tm + i) * C_ + bo + tn) = v;
  }
}

// ---------------------------------------------------------------------------
extern "C" void kernel_launch(void* const* d_in, const int* in_sizes, int n_in,
                              void* d_out, int out_size, void* d_ws, size_t ws_size,
                              hipStream_t stream) {
  (void)in_sizes; (void)n_in; (void)out_size; (void)ws_size;
  const float* x  = (const float*)d_in[0];
  // d_in[1] = bank (unused by forward)
  const float* Wq = (const float*)d_in[2];
  const float* WE = (const float*)d_in[3];
  const float* bE = (const float*)d_in[4];
  const float* t1 = (const float*)d_in[5];
  const float* t2 = (const float*)d_in[6];
  const float* W1 = (const float*)d_in[7];
  const float* b1 = (const float*)d_in[8];
  const float* W2 = (const float*)d_in[9];
  const float* b2 = (const float*)d_in[10];
  const float* pa = (const float*)d_in[11];
  float* out = (float*)d_out;

  float* ws = (float*)d_ws;
  size_t off = 0;
  float* qkvv = ws + off; off += (size_t)M_ * OC_;      // 33,554,432
  float* xsa  = ws + off; off += (size_t)M_ * C_;       //  8,388,608
  float* xca  = ws + off; off += (size_t)M_ * C_;       //  8,388,608
  float* wet  = ws + off; off += (size_t)N_ * P_;       //    262,144
  float* Sqk  = ws + off; off += (size_t)B_ * H_ * D_ * D_;  // 131,072
  float* kp   = ws + off; off += (size_t)B_ * H_ * D_ * P_;  // 131,072 ([p][d])
  float* vp   = ws + off; off += (size_t)B_ * H_ * D_ * P_;  // 131,072 ([d][p])
  float* ssq  = ws + off; off += (size_t)B_ * 512;      //      4,096
  float* rn   = ws + off; off += (size_t)B_ * 512;      //      4,096

  // Zero the atomically-accumulated buffers (Sqk,kp,vp,ssq are contiguous).
  hipMemsetAsync(Sqk, 0, (size_t)(3 * 131072 + 4096) * sizeof(float), stream);

  k_wet<<<64, 256, 0, stream>>>(WE, wet);
  k_qkvv<<<dim3(M_ / 64, OC_ / 64), 256, 0, stream>>>(x, Wq, qkvv);
  k_norms_partial<<<dim3(16, 8), 256, 0, stream>>>(qkvv, ssq);
  k_norms_final<<<16, 256, 0, stream>>>(ssq, rn);
  k_pair<<<dim3(32, 3, 8), 256, 0, stream>>>(qkvv, wet, Sqk, kp, vp);
  k_ca_softmax<<<512, 256, 0, stream>>>(Sqk, rn, t1);
  k_ca_apply<<<dim3(32, 64), 256, 0, stream>>>(qkvv, Sqk, xca);
  k_sa<<<dim3(32, 64), 256, 0, stream>>>(qkvv, kp, vp, bE, rn, t2, xsa);
  k_out<<<dim3(M_ / 64, 4), 256, 0, stream>>>(xsa, xca, W1, b1, W2, b2, pa, out);
}

// Round 3
// 391.810 us; speedup vs baseline: 2.2087x; 1.5281x over previous
//
#include <hip/hip_runtime.h>
#include <cstdint>
#include <cstddef>

// Problem constants (fixed by reference)
constexpr int B_ = 8, N_ = 4096, C_ = 256, H_ = 4, D_ = 64, P_ = 64;
constexpr int OC_ = 4 * C_;      // 1024 qkvv channels
constexpr int M_  = B_ * N_;     // 32768 tokens

#define DEV_INLINE __device__ __forceinline__

typedef __attribute__((ext_vector_type(8))) short short8;    // 8 bf16 = 4 VGPR
typedef __attribute__((ext_vector_type(4))) short short4v;   // 4 bf16 = 8 B
typedef __attribute__((ext_vector_type(4))) float floatx4;   // MFMA acc

DEV_INLINE short f2bf(float f) {  // RNE f32 -> bf16
  unsigned int u = __builtin_bit_cast(unsigned int, f);
  u += 0x7FFFu + ((u >> 16) & 1u);
  return (short)(u >> 16);
}

// ---------------------------------------------------------------------------
// Shared MFMA tile core: C[128x128] += A[128xK=256] * Bw[128x256]^T, both f32
// k-contiguous in HBM, converted to bf16 during LDS staging.
// LDS rows padded to 72 shorts: fragment b128 reads 2-way (free), b64 writes
// conflict-free. 4 waves in 2x2, each 64x64 via 4x4 of 16x16x32 bf16 MFMA.
DEV_INLINE void mfma_core(const float* __restrict__ A, const float* __restrict__ Bw,
                          int bm, short* As, short* Bs, floatx4 acc[4][4]) {
  const int t = threadIdx.x;
  const int c4 = t & 15;          // float4 column within 64-wide k-chunk
  const int lane = t & 63;
  const int wave = t >> 6;
  const int m16 = lane & 15;
  const int quad = lane >> 4;
  const int wm = (wave >> 1) << 6;
  const int wn = (wave & 1) << 6;
  const float4* A4 = (const float4*)A;
  const float4* B4 = (const float4*)Bw;
#pragma unroll 1
  for (int k0 = 0; k0 < 256; k0 += 64) {
    const int kq = k0 >> 2;
    float4 av[8], bv[8];
#pragma unroll
    for (int j = 0; j < 8; ++j) {
      const int r = (t >> 4) + 16 * j;
      av[j] = A4[(size_t)(bm + r) * 64 + kq + c4];
      bv[j] = B4[(size_t)r * 64 + kq + c4];
    }
    __syncthreads();                 // prev iter's LDS reads done
#pragma unroll
    for (int j = 0; j < 8; ++j) {
      const int r = (t >> 4) + 16 * j;
      short4v a4s = {f2bf(av[j].x), f2bf(av[j].y), f2bf(av[j].z), f2bf(av[j].w)};
      short4v b4s = {f2bf(bv[j].x), f2bf(bv[j].y), f2bf(bv[j].z), f2bf(bv[j].w)};
      *(short4v*)&As[r * 72 + c4 * 4] = a4s;
      *(short4v*)&Bs[r * 72 + c4 * 4] = b4s;
    }
    __syncthreads();
#pragma unroll
    for (int ks = 0; ks < 2; ++ks) {
      short8 af[4], bf[4];
#pragma unroll
      for (int i = 0; i < 4; ++i)
        af[i] = *(const short8*)&As[(wm + i * 16 + m16) * 72 + ks * 32 + quad * 8];
#pragma unroll
      for (int j = 0; j < 4; ++j)
        bf[j] = *(const short8*)&Bs[(wn + j * 16 + m16) * 72 + ks * 32 + quad * 8];
#pragma unroll
      for (int i = 0; i < 4; ++i)
#pragma unroll
        for (int j = 0; j < 4; ++j)
          acc[i][j] = __builtin_amdgcn_mfma_f32_16x16x32_bf16(af[i], bf[j], acc[i][j], 0, 0, 0);
    }
  }
}

// ---------------------------------------------------------------------------
// qkvv = x @ W_qkvv^T : [32768,256] x [1024,256]^T -> [32768,1024] (f32 out)
__global__ __launch_bounds__(256) void k_qkvv_mfma(const float* __restrict__ x,
                                                   const float* __restrict__ W,
                                                   float* __restrict__ out) {
  __shared__ __align__(16) short As[128 * 72];
  __shared__ __align__(16) short Bs[128 * 72];
  const int bm = blockIdx.x * 128;
  const int bo = blockIdx.y * 128;
  floatx4 acc[4][4];
#pragma unroll
  for (int i = 0; i < 4; ++i)
#pragma unroll
    for (int j = 0; j < 4; ++j) acc[i][j] = (floatx4)(0.f);
  mfma_core(x, W + (size_t)bo * 256, bm, As, Bs, acc);
  const int lane = threadIdx.x & 63, wave = threadIdx.x >> 6;
  const int m16 = lane & 15, quad = lane >> 4;
  const int wm = (wave >> 1) << 6, wn = (wave & 1) << 6;
#pragma unroll
  for (int i = 0; i < 4; ++i)
#pragma unroll
    for (int r = 0; r < 4; ++r) {
      const int gr = bm + wm + i * 16 + quad * 4 + r;
#pragma unroll
      for (int j = 0; j < 4; ++j)
        out[(size_t)gr * OC_ + bo + wn + j * 16 + m16] = acc[i][j][r];
    }
}

// ---------------------------------------------------------------------------
// out[:, half*128 + 0:128] = PReLU(A @ W^T + bias), A = xsa (half 0) / xca (1)
__global__ __launch_bounds__(256) void k_out_mfma(const float* __restrict__ xsa,
                                                  const float* __restrict__ xca,
                                                  const float* __restrict__ W1,
                                                  const float* __restrict__ b1,
                                                  const float* __restrict__ W2,
                                                  const float* __restrict__ b2,
                                                  const float* __restrict__ pa,
                                                  float* __restrict__ out) {
  __shared__ __align__(16) short As[128 * 72];
  __shared__ __align__(16) short Bs[128 * 72];
  const int bm = blockIdx.x * 128;
  const int half = blockIdx.y;
  const float* A = half ? xca : xsa;
  const float* W = half ? W2 : W1;
  const float* bias = half ? b2 : b1;
  floatx4 acc[4][4];
#pragma unroll
  for (int i = 0; i < 4; ++i)
#pragma unroll
    for (int j = 0; j < 4; ++j) acc[i][j] = (floatx4)(0.f);
  mfma_core(A, W, bm, As, Bs, acc);
  const float slope = pa[0];
  const int lane = threadIdx.x & 63, wave = threadIdx.x >> 6;
  const int m16 = lane & 15, quad = lane >> 4;
  const int wm = (wave >> 1) << 6, wn = (wave & 1) << 6;
  float bj[4];
#pragma unroll
  for (int j = 0; j < 4; ++j) bj[j] = bias[wn + j * 16 + m16];
#pragma unroll
  for (int i = 0; i < 4; ++i)
#pragma unroll
    for (int r = 0; r < 4; ++r) {
      const int gr = bm + wm + i * 16 + quad * 4 + r;
#pragma unroll
      for (int j = 0; j < 4; ++j) {
        float v = acc[i][j][r] + bj[j];
        v = v >= 0.f ? v : slope * v;
        out[(size_t)gr * C_ + half * 128 + wn + j * 16 + m16] = v;
      }
    }
}

// ---------------------------------------------------------------------------
// Transpose W_E [P][N] -> WET [N][P] for coalesced n-major loads in k_pair.
__global__ __launch_bounds__(256) void k_wet(const float* __restrict__ WE,
                                             float* __restrict__ wet) {
  __shared__ float t_s[64][65];
  const int n0 = blockIdx.x * 64;
  const int t = threadIdx.x;
#pragma unroll
  for (int j = 0; j < 16; ++j) {
    int idx = t + j * 256;
    int p = idx >> 6, nl = idx & 63;
    t_s[p][nl] = WE[(size_t)p * N_ + n0 + nl];
  }
  __syncthreads();
#pragma unroll
  for (int j = 0; j < 16; ++j) {
    int idx = t + j * 256;
    int nl = idx >> 6, p = idx & 63;
    wet[(size_t)(n0 + nl) * P_ + p] = t_s[p][nl];
  }
}

// ---------------------------------------------------------------------------
// Token-axis sum-of-squares for q (channels 0..255) and k (channels 256..511).
__global__ __launch_bounds__(256) void k_norms_partial(const float* __restrict__ qkvv,
                                                       float* __restrict__ ssq) {
  const int g = blockIdx.x;           // b*2 + half
  const int b = g >> 1, half = g & 1;
  const int n0 = blockIdx.y * 512;
  const int c = threadIdx.x;          // 0..255
  const float* p = qkvv + (size_t)b * N_ * OC_ + half * 256 + c;
  float ss = 0.f;
  for (int n = 0; n < 512; ++n) {
    float v = p[(size_t)(n0 + n) * OC_];
    ss += v * v;
  }
  atomicAdd(&ssq[(size_t)b * 512 + half * 256 + c], ss);
}

__global__ void k_norms_final(const float* __restrict__ ssq, float* __restrict__ rn) {
  const int i = blockIdx.x * 256 + threadIdx.x;  // 4096
  rn[i] = 1.f / fmaxf(sqrtf(ssq[i]), 1e-12f);
}

// ---------------------------------------------------------------------------
// Per-(b,h) contractions over tokens: op0 S_qk = q.k^T ([d][e]),
// op1 k_proj = k.WET stored TRANSPOSED as [p][d], op2 v_proj = v_sa.WET [d][p].
__global__ __launch_bounds__(256) void k_pair(const float* __restrict__ qkvv,
                                              const float* __restrict__ wet,
                                              float* __restrict__ Sqk,
                                              float* __restrict__ kp,
                                              float* __restrict__ vp) {
  __shared__ float At[64][68];
  __shared__ float Bt[64][68];
  const int bh = blockIdx.x;  // 0..31
  const int op = blockIdx.y;  // 0..2
  const int nc = blockIdx.z;  // 0..7
  const int b = bh >> 2, h = bh & 3;
  const int t = threadIdx.x;
  const size_t qbase = (size_t)b * N_ * OC_;
  const float* Abase;
  const float* Bbase;
  size_t Bstride;
  float* out;
  if (op == 0) {
    Abase = qkvv + qbase + h * 64;
    Bbase = qkvv + qbase + 256 + h * 64; Bstride = OC_;
    out = Sqk;
  } else if (op == 1) {
    Abase = qkvv + qbase + 256 + h * 64;
    Bbase = wet; Bstride = P_;
    out = kp;
  } else {
    Abase = qkvv + qbase + 768 + h * 64;
    Bbase = wet; Bstride = P_;
    out = vp;
  }
  out += (size_t)bh * 64 * 64;
  const int ch = t & 63;
  const int nr = t >> 6;            // 0..3
  const int ta = (t & 15) << 2;
  const int tb = (t >> 4) << 2;
  float acc[4][4] = {};
  for (int s = 0; s < 8; ++s) {
    const int n0 = nc * 512 + s * 64;
    __syncthreads();
#pragma unroll
    for (int j = 0; j < 16; ++j) {
      int nl = nr + 4 * j;
      At[nl][ch] = Abase[(size_t)(n0 + nl) * OC_ + ch];
      Bt[nl][ch] = Bbase[(size_t)(n0 + nl) * Bstride + ch];
    }
    __syncthreads();
#pragma unroll 8
    for (int nn = 0; nn < 64; ++nn) {
      const float4 a4 = *(const float4*)&At[nn][ta];
      const float4 b4 = *(const float4*)&Bt[nn][tb];
      const float a[4] = {a4.x, a4.y, a4.z, a4.w};
      const float bb[4] = {b4.x, b4.y, b4.z, b4.w};
#pragma unroll
      for (int i = 0; i < 4; ++i)
#pragma unroll
        for (int j = 0; j < 4; ++j) acc[i][j] += a[i] * bb[j];
    }
  }
  if (op == 1) {
#pragma unroll
    for (int i = 0; i < 4; ++i)
#pragma unroll
      for (int j = 0; j < 4; ++j)
        atomicAdd(&out[(size_t)(tb + j) * 64 + ta + i], acc[i][j]);  // [p][d]
  } else {
#pragma unroll
    for (int i = 0; i < 4; ++i)
#pragma unroll
      for (int j = 0; j < 4; ++j)
        atomicAdd(&out[(size_t)(ta + i) * 64 + tb + j], acc[i][j]);
  }
}

// ---------------------------------------------------------------------------
// Channel-attn softmax: logits = S_qk * rq[dd] * rk[e] * temp[h], softmax over e.
__global__ __launch_bounds__(256) void k_ca_softmax(float* __restrict__ Sqk,
                                                    const float* __restrict__ rn,
                                                    const float* __restrict__ temp) {
  const int w = threadIdx.x >> 6;
  const int lane = threadIdx.x & 63;
  const int row = blockIdx.x * 4 + w;  // 0..2047 == b*256 + h*64 + dd
  const int b = row >> 8;
  const int rem = row & 255;
  const int h = rem >> 6;
  const float rq = rn[b * 512 + rem];
  const float rk = rn[b * 512 + 256 + h * 64 + lane];
  float l = Sqk[(size_t)row * 64 + lane] * rq * rk * temp[h];
  float m = l;
#pragma unroll
  for (int o = 32; o; o >>= 1) m = fmaxf(m, __shfl_xor(m, o));
  const float e = __expf(l - m);
  float s = e;
#pragma unroll
  for (int o = 32; o; o >>= 1) s += __shfl_xor(s, o);
  Sqk[(size_t)row * 64 + lane] = e / s;
}

// ---------------------------------------------------------------------------
// x_ca[b,n,h*64+d] = sum_e attn[b,h,d,e] * qkvv[n][512+h*64+e].
// 64-token tile; LDS-tiled 4x4 register GEMM (rows strided by 16 -> 2-way free).
__global__ __launch_bounds__(256) void k_ca_apply(const float* __restrict__ qkvv,
                                                  const float* __restrict__ attn,
                                                  float* __restrict__ x_ca) {
  __shared__ float Vs[64][68];   // [tok][e]
  __shared__ float As[64][68];   // [d][e]
  const int bh = blockIdx.x;
  const int b = bh >> 2, h = bh & 3;
  const int n0 = blockIdx.y * 64;
  const int t = threadIdx.x;
#pragma unroll
  for (int j = 0; j < 4; ++j) {
    int i4 = t + j * 256;          // float4 index 0..1023
    int row = i4 >> 4;
    int c0 = (i4 & 15) << 2;
    *(float4*)&As[row][c0] = *(const float4*)&attn[(size_t)bh * 4096 + (size_t)i4 * 4];
    *(float4*)&Vs[row][c0] =
        *(const float4*)&qkvv[(size_t)(b * N_ + n0 + row) * OC_ + 512 + h * 64 + c0];
  }
  __syncthreads();
  const int tm = t & 15;           // token rows tm+16*i
  const int tn = (t >> 4) << 2;    // channel cols
  float acc[4][4] = {};
#pragma unroll
  for (int e0 = 0; e0 < 64; e0 += 4) {
    float4 a4[4], b4[4];
#pragma unroll
    for (int i = 0; i < 4; ++i) a4[i] = *(const float4*)&Vs[tm + 16 * i][e0];
#pragma unroll
    for (int j = 0; j < 4; ++j) b4[j] = *(const float4*)&As[tn + j][e0];
#pragma unroll
    for (int i = 0; i < 4; ++i)
#pragma unroll
      for (int j = 0; j < 4; ++j)
        acc[i][j] += a4[i].x * b4[j].x + a4[i].y * b4[j].y +
                     a4[i].z * b4[j].z + a4[i].w * b4[j].w;
  }
#pragma unroll
  for (int i = 0; i < 4; ++i) {
    float4 v;
    v.x = acc[i][0]; v.y = acc[i][1]; v.z = acc[i][2]; v.w = acc[i][3];
    *(float4*)&x_ca[(size_t)(b * N_ + n0 + tm + 16 * i) * C_ + h * 64 + tn] = v;
  }
}

// ---------------------------------------------------------------------------
// Spatial attention, tiled: per (bh, 64-token tile):
//   S[tok][p] = sum_d Q[tok][d] * Ks[p][d]   (rq, t2, bE folded into Ks)
//   softmax rows of S over p
//   O[tok][d] = sum_p S[tok][p] * Vs[d][p]   (bE folded into Vs)
// kpT comes in [p][d]; vp comes in [d][p].
__global__ __launch_bounds__(256) void k_sa(const float* __restrict__ qkvv,
                                            const float* __restrict__ kpT,
                                            const float* __restrict__ vp,
                                            const float* __restrict__ bE,
                                            const float* __restrict__ rn,
                                            const float* __restrict__ temp2,
                                            float* __restrict__ x_sa) {
  __shared__ float Qs[64][68];   // [tok][d]; re-used as S [tok][p] after GEMM1
  __shared__ float Ks[64][68];   // [p][d] scaled
  __shared__ float Vs[64][68];   // [d][p] + bE
  const int bh = blockIdx.x;
  const int b = bh >> 2, h = bh & 3;
  const int n0 = blockIdx.y * 64;
  const int t = threadIdx.x;
  const float t2 = temp2[h];
#pragma unroll
  for (int j = 0; j < 4; ++j) {
    int i4 = t + j * 256;
    int row = i4 >> 4;             // p for Ks, d for Vs, tok for Qs
    int c0 = (i4 & 15) << 2;
    float4 kv = *(const float4*)&kpT[(size_t)bh * 4096 + (size_t)i4 * 4];
    float4 vv = *(const float4*)&vp[(size_t)bh * 4096 + (size_t)i4 * 4];
    const float be_r = bE[row];
    Ks[row][c0 + 0] = (kv.x + be_r) * rn[b * 512 + h * 64 + c0 + 0] * t2;
    Ks[row][c0 + 1] = (kv.y + be_r) * rn[b * 512 + h * 64 + c0 + 1] * t2;
    Ks[row][c0 + 2] = (kv.z + be_r) * rn[b * 512 + h * 64 + c0 + 2] * t2;
    Ks[row][c0 + 3] = (kv.w + be_r) * rn[b * 512 + h * 64 + c0 + 3] * t2;
    Vs[row][c0 + 0] = vv.x + bE[c0 + 0];
    Vs[row][c0 + 1] = vv.y + bE[c0 + 1];
    Vs[row][c0 + 2] = vv.z + bE[c0 + 2];
    Vs[row][c0 + 3] = vv.w + bE[c0 + 3];
    *(float4*)&Qs[row][c0] =
        *(const float4*)&qkvv[(size_t)(b * N_ + n0 + row) * OC_ + h * 64 + c0];
  }
  __syncthreads();
  const int tm = t & 15;           // token rows tm+16*i
  const int tn = (t >> 4) << 2;    // output cols (p in GEMM1, d in GEMM2)
  float acc[4][4] = {};
#pragma unroll
  for (int d0 = 0; d0 < 64; d0 += 4) {
    float4 a4[4], b4[4];
#pragma unroll
    for (int i = 0; i < 4; ++i) a4[i] = *(const float4*)&Qs[tm + 16 * i][d0];
#pragma unroll
    for (int j = 0; j < 4; ++j) b4[j] = *(const float4*)&Ks[tn + j][d0];
#pragma unroll
    for (int i = 0; i < 4; ++i)
#pragma unroll
      for (int j = 0; j < 4; ++j)
        acc[i][j] += a4[i].x * b4[j].x + a4[i].y * b4[j].y +
                     a4[i].z * b4[j].z + a4[i].w * b4[j].w;
  }
  __syncthreads();                 // all Qs reads done; safe to alias
  float(*Ss)[68] = Qs;
#pragma unroll
  for (int i = 0; i < 4; ++i) {
    float4 v;
    v.x = acc[i][0]; v.y = acc[i][1]; v.z = acc[i][2]; v.w = acc[i][3];
    *(float4*)&Ss[tm + 16 * i][tn] = v;
  }
  __syncthreads();
  // softmax: 4 threads per row, 16 elems each
  {
    const int r = t >> 2;
    const int s0 = (t & 3) << 4;
    float4 v0 = *(float4*)&Ss[r][s0 + 0];
    float4 v1 = *(float4*)&Ss[r][s0 + 4];
    float4 v2 = *(float4*)&Ss[r][s0 + 8];
    float4 v3 = *(float4*)&Ss[r][s0 + 12];
    float m = fmaxf(fmaxf(fmaxf(v0.x, v0.y), fmaxf(v0.z, v0.w)),
                    fmaxf(fmaxf(v1.x, v1.y), fmaxf(v1.z, v1.w)));
    m = fmaxf(m, fmaxf(fmaxf(fmaxf(v2.x, v2.y), fmaxf(v2.z, v2.w)),
                       fmaxf(fmaxf(v3.x, v3.y), fmaxf(v3.z, v3.w))));
    m = fmaxf(m, __shfl_xor(m, 1));
    m = fmaxf(m, __shfl_xor(m, 2));
    v0.x = __expf(v0.x - m); v0.y = __expf(v0.y - m);
    v0.z = __expf(v0.z - m); v0.w = __expf(v0.w - m);
    v1.x = __expf(v1.x - m); v1.y = __expf(v1.y - m);
    v1.z = __expf(v1.z - m); v1.w = __expf(v1.w - m);
    v2.x = __expf(v2.x - m); v2.y = __expf(v2.y - m);
    v2.z = __expf(v2.z - m); v2.w = __expf(v2.w - m);
    v3.x = __expf(v3.x - m); v3.y = __expf(v3.y - m);
    v3.z = __expf(v3.z - m); v3.w = __expf(v3.w - m);
    float s = (v0.x + v0.y + v0.z + v0.w) + (v1.x + v1.y + v1.z + v1.w) +
              (v2.x + v2.y + v2.z + v2.w) + (v3.x + v3.y + v3.z + v3.w);
    s += __shfl_xor(s, 1);
    s += __shfl_xor(s, 2);
    const float inv = 1.f / s;
    v0.x *= inv; v0.y *= inv; v0.z *= inv; v0.w *= inv;
    v1.x *= inv; v1.y *= inv; v1.z *= inv; v1.w *= inv;
    v2.x *= inv; v2.y *= inv; v2.z *= inv; v2.w *= inv;
    v3.x *= inv; v3.y *= inv; v3.z *= inv; v3.w *= inv;
    *(float4*)&Ss[r][s0 + 0] = v0;
    *(float4*)&Ss[r][s0 + 4] = v1;
    *(float4*)&Ss[r][s0 + 8] = v2;
    *(float4*)&Ss[r][s0 + 12] = v3;
  }
  __syncthreads();
  float acc2[4][4] = {};
#pragma unroll
  for (int p0 = 0; p0 < 64; p0 += 4) {
    float4 a4[4], b4[4];
#pragma unroll
    for (int i = 0; i < 4; ++i) a4[i] = *(const float4*)&Ss[tm + 16 * i][p0];
#pragma unroll
    for (int j = 0; j < 4; ++j) b4[j] = *(const float4*)&Vs[tn + j][p0];
#pragma unroll
    for (int i = 0; i < 4; ++i)
#pragma unroll
      for (int j = 0; j < 4; ++j)
        acc2[i][j] += a4[i].x * b4[j].x + a4[i].y * b4[j].y +
                      a4[i].z * b4[j].z + a4[i].w * b4[j].w;
  }
#pragma unroll
  for (int i = 0; i < 4; ++i) {
    float4 v;
    v.x = acc2[i][0]; v.y = acc2[i][1]; v.z = acc2[i][2]; v.w = acc2[i][3];
    *(float4*)&x_sa[(size_t)(b * N_ + n0 + tm + 16 * i) * C_ + h * 64 + tn] = v;
  }
}

// ---------------------------------------------------------------------------
extern "C" void kernel_launch(void* const* d_in, const int* in_sizes, int n_in,
                              void* d_out, int out_size, void* d_ws, size_t ws_size,
                              hipStream_t stream) {
  (void)in_sizes; (void)n_in; (void)out_size; (void)ws_size;
  const float* x  = (const float*)d_in[0];
  // d_in[1] = bank (unused by forward)
  const float* Wq = (const float*)d_in[2];
  const float* WE = (const float*)d_in[3];
  const float* bE = (const float*)d_in[4];
  const float* t1 = (const float*)d_in[5];
  const float* t2 = (const float*)d_in[6];
  const float* W1 = (const float*)d_in[7];
  const float* b1 = (const float*)d_in[8];
  const float* W2 = (const float*)d_in[9];
  const float* b2 = (const float*)d_in[10];
  const float* pa = (const float*)d_in[11];
  float* out = (float*)d_out;

  float* ws = (float*)d_ws;
  size_t off = 0;
  float* qkvv = ws + off; off += (size_t)M_ * OC_;      // 33,554,432
  float* xsa  = ws + off; off += (size_t)M_ * C_;       //  8,388,608
  float* xca  = ws + off; off += (size_t)M_ * C_;       //  8,388,608
  float* wet  = ws + off; off += (size_t)N_ * P_;       //    262,144
  float* Sqk  = ws + off; off += (size_t)B_ * H_ * D_ * D_;  // 131,072
  float* kp   = ws + off; off += (size_t)B_ * H_ * D_ * P_;  // 131,072 ([p][d])
  float* vp   = ws + off; off += (size_t)B_ * H_ * D_ * P_;  // 131,072 ([d][p])
  float* ssq  = ws + off; off += (size_t)B_ * 512;      //      4,096
  float* rn   = ws + off; off += (size_t)B_ * 512;      //      4,096

  // Zero the atomically-accumulated buffers (Sqk,kp,vp,ssq are contiguous).
  hipMemsetAsync(Sqk, 0, (size_t)(3 * 131072 + 4096) * sizeof(float), stream);

  k_wet<<<64, 256, 0, stream>>>(WE, wet);
  k_qkvv_mfma<<<dim3(M_ / 128, OC_ / 128), 256, 0, stream>>>(x, Wq, qkvv);
  k_norms_partial<<<dim3(16, 8), 256, 0, stream>>>(qkvv, ssq);
  k_norms_final<<<16, 256, 0, stream>>>(ssq, rn);
  k_pair<<<dim3(32, 3, 8), 256, 0, stream>>>(qkvv, wet, Sqk, kp, vp);
  k_ca_softmax<<<512, 256, 0, stream>>>(Sqk, rn, t1);
  k_ca_apply<<<dim3(32, 64), 256, 0, stream>>>(qkvv, Sqk, xca);
  k_sa<<<dim3(32, 64), 256, 0, stream>>>(qkvv, kp, vp, bE, rn, t2, xsa);
  k_out_mfma<<<dim3(M_ / 128, 2), 256, 0, stream>>>(xsa, xca, W1, b1, W2, b2, pa, out);
}

// Round 4
// 383.141 us; speedup vs baseline: 2.2587x; 1.0226x over previous
//
#include <hip/hip_runtime.h>
#include <cstdint>
#include <cstddef>

// Problem constants (fixed by reference)
constexpr int B_ = 8, N_ = 4096, C_ = 256, H_ = 4, D_ = 64, P_ = 64;
constexpr int OC_ = 4 * C_;      // 1024 qkvv channels
constexpr int M_  = B_ * N_;     // 32768 tokens

#define DEV_INLINE __device__ __forceinline__

typedef unsigned short ushort_t;
typedef __attribute__((ext_vector_type(8))) short short8;    // 8 bf16 = 4 VGPR
typedef __attribute__((ext_vector_type(4))) short short4v;   // 4 bf16 = 8 B
typedef __attribute__((ext_vector_type(4))) float floatx4;   // MFMA acc

DEV_INLINE short f2bf(float f) {  // RNE f32 -> bf16
  unsigned int u = __builtin_bit_cast(unsigned int, f);
  u += 0x7FFFu + ((u >> 16) & 1u);
  return (short)(u >> 16);
}
DEV_INLINE float bf2f(ushort_t s) {
  return __builtin_bit_cast(float, (unsigned int)s << 16);
}

// ---------------------------------------------------------------------------
// Shared MFMA tile core: C[128x128] += A[128x256] * Bw[128x256]^T, both f32
// k-contiguous in HBM, converted to bf16 during LDS staging (stride 72).
DEV_INLINE void mfma_core(const float* __restrict__ A, const float* __restrict__ Bw,
                          int bm, short* As, short* Bs, floatx4 acc[4][4]) {
  const int t = threadIdx.x;
  const int c4 = t & 15;
  const int lane = t & 63;
  const int wave = t >> 6;
  const int m16 = lane & 15;
  const int quad = lane >> 4;
  const int wm = (wave >> 1) << 6;
  const int wn = (wave & 1) << 6;
  const float4* A4 = (const float4*)A;
  const float4* B4 = (const float4*)Bw;
#pragma unroll 1
  for (int k0 = 0; k0 < 256; k0 += 64) {
    const int kq = k0 >> 2;
    float4 av[8], bv[8];
#pragma unroll
    for (int j = 0; j < 8; ++j) {
      const int r = (t >> 4) + 16 * j;
      av[j] = A4[(size_t)(bm + r) * 64 + kq + c4];
      bv[j] = B4[(size_t)r * 64 + kq + c4];
    }
    __syncthreads();
#pragma unroll
    for (int j = 0; j < 8; ++j) {
      const int r = (t >> 4) + 16 * j;
      short4v a4s = {f2bf(av[j].x), f2bf(av[j].y), f2bf(av[j].z), f2bf(av[j].w)};
      short4v b4s = {f2bf(bv[j].x), f2bf(bv[j].y), f2bf(bv[j].z), f2bf(bv[j].w)};
      *(short4v*)&As[r * 72 + c4 * 4] = a4s;
      *(short4v*)&Bs[r * 72 + c4 * 4] = b4s;
    }
    __syncthreads();
#pragma unroll
    for (int ks = 0; ks < 2; ++ks) {
      short8 af[4], bf[4];
#pragma unroll
      for (int i = 0; i < 4; ++i)
        af[i] = *(const short8*)&As[(wm + i * 16 + m16) * 72 + ks * 32 + quad * 8];
#pragma unroll
      for (int j = 0; j < 4; ++j)
        bf[j] = *(const short8*)&Bs[(wn + j * 16 + m16) * 72 + ks * 32 + quad * 8];
#pragma unroll
      for (int i = 0; i < 4; ++i)
#pragma unroll
        for (int j = 0; j < 4; ++j)
          acc[i][j] = __builtin_amdgcn_mfma_f32_16x16x32_bf16(af[i], bf[j], acc[i][j], 0, 0, 0);
    }
  }
}

// ---------------------------------------------------------------------------
// qkvv = x @ W_qkvv^T : [32768,256] x [1024,256]^T -> [32768,1024], bf16 out
__global__ __launch_bounds__(256) void k_qkvv_mfma(const float* __restrict__ x,
                                                   const float* __restrict__ W,
                                                   ushort_t* __restrict__ outb) {
  __shared__ __align__(16) short As[128 * 72];
  __shared__ __align__(16) short Bs[128 * 72];
  const int bm = blockIdx.x * 128;
  const int bo = blockIdx.y * 128;
  floatx4 acc[4][4];
#pragma unroll
  for (int i = 0; i < 4; ++i)
#pragma unroll
    for (int j = 0; j < 4; ++j) acc[i][j] = (floatx4)(0.f);
  mfma_core(x, W + (size_t)bo * 256, bm, As, Bs, acc);
  const int lane = threadIdx.x & 63, wave = threadIdx.x >> 6;
  const int m16 = lane & 15, quad = lane >> 4;
  const int wm = (wave >> 1) << 6, wn = (wave & 1) << 6;
#pragma unroll
  for (int i = 0; i < 4; ++i)
#pragma unroll
    for (int r = 0; r < 4; ++r) {
      const int gr = bm + wm + i * 16 + quad * 4 + r;
#pragma unroll
      for (int j = 0; j < 4; ++j)
        outb[(size_t)gr * OC_ + bo + wn + j * 16 + m16] = (ushort_t)f2bf(acc[i][j][r]);
    }
}

// ---------------------------------------------------------------------------
// out[:, half*128 + 0:128] = PReLU(A @ W^T + bias), A = xsa (half 0) / xca (1)
__global__ __launch_bounds__(256) void k_out_mfma(const float* __restrict__ xsa,
                                                  const float* __restrict__ xca,
                                                  const float* __restrict__ W1,
                                                  const float* __restrict__ b1,
                                                  const float* __restrict__ W2,
                                                  const float* __restrict__ b2,
                                                  const float* __restrict__ pa,
                                                  float* __restrict__ out) {
  __shared__ __align__(16) short As[128 * 72];
  __shared__ __align__(16) short Bs[128 * 72];
  const int bm = blockIdx.x * 128;
  const int half = blockIdx.y;
  const float* A = half ? xca : xsa;
  const float* W = half ? W2 : W1;
  const float* bias = half ? b2 : b1;
  floatx4 acc[4][4];
#pragma unroll
  for (int i = 0; i < 4; ++i)
#pragma unroll
    for (int j = 0; j < 4; ++j) acc[i][j] = (floatx4)(0.f);
  mfma_core(A, W, bm, As, Bs, acc);
  const float slope = pa[0];
  const int lane = threadIdx.x & 63, wave = threadIdx.x >> 6;
  const int m16 = lane & 15, quad = lane >> 4;
  const int wm = (wave >> 1) << 6, wn = (wave & 1) << 6;
  float bj[4];
#pragma unroll
  for (int j = 0; j < 4; ++j) bj[j] = bias[wn + j * 16 + m16];
#pragma unroll
  for (int i = 0; i < 4; ++i)
#pragma unroll
    for (int r = 0; r < 4; ++r) {
      const int gr = bm + wm + i * 16 + quad * 4 + r;
#pragma unroll
      for (int j = 0; j < 4; ++j) {
        float v = acc[i][j][r] + bj[j];
        v = v >= 0.f ? v : slope * v;
        out[(size_t)gr * C_ + half * 128 + wn + j * 16 + m16] = v;
      }
    }
}

// ---------------------------------------------------------------------------
// Token-axis sum-of-squares for q (channels 0..255) and k (channels 256..511).
__global__ __launch_bounds__(256) void k_norms_partial(const ushort_t* __restrict__ qkvv,
                                                       float* __restrict__ ssq) {
  const int g = blockIdx.x;           // b*2 + half
  const int b = g >> 1, half = g & 1;
  const int n0 = blockIdx.y * 512;
  const int c = threadIdx.x;          // 0..255
  const ushort_t* p = qkvv + (size_t)b * N_ * OC_ + half * 256 + c;
  float ss = 0.f;
  for (int n = 0; n < 512; ++n) {
    float v = bf2f(p[(size_t)(n0 + n) * OC_]);
    ss += v * v;
  }
  atomicAdd(&ssq[(size_t)b * 512 + half * 256 + c], ss);
}

__global__ void k_norms_final(const float* __restrict__ ssq, float* __restrict__ rn) {
  const int i = blockIdx.x * 256 + threadIdx.x;  // 4096
  rn[i] = 1.f / fmaxf(sqrtf(ssq[i]), 1e-12f);
}

// ---------------------------------------------------------------------------
// Fused per-(b,h) contractions over tokens, MFMA version.
//   op0: Sqk[d][e] += sum_n Q[n][d] K[n][e]
//   op1: kp [p][d] += sum_n K[n][d] WE[p][n]   (stored transposed for k_sa)
//   op2: vp [d][p] += sum_n V[n][d] WE[p][n]
// Tiles staged in LDS as [ch][tok] bf16 (stride 72); WE is natively [p][n] so
// needs no transpose. K-tile fragments serve as both op0-B and op1-A.
// Grid: (bh=32, nc=16), each block reduces 256 tokens via 4 chunks of 64.
__global__ __launch_bounds__(256) void k_pair_mfma(const ushort_t* __restrict__ qkvv,
                                                   const float* __restrict__ WE,
                                                   float* __restrict__ Sqk,
                                                   float* __restrict__ kp,
                                                   float* __restrict__ vp) {
  __shared__ __align__(16) short Qt[64 * 72];
  __shared__ __align__(16) short Kt[64 * 72];
  __shared__ __align__(16) short Vt[64 * 72];
  __shared__ __align__(16) short Wt[64 * 72];
  const int bh = blockIdx.x;
  const int nc = blockIdx.y;
  const int b = bh >> 2, h = bh & 3;
  const int t = threadIdx.x;
  const int lane = t & 63, wave = t >> 6;
  const int m16 = lane & 15, quad = lane >> 4;
  const int c0 = (t & 15) << 2;    // channel quad for staging
  const int tp = t >> 4;           // token-pair id 0..15
  floatx4 acc0[4], acc1[4], acc2[4];
#pragma unroll
  for (int j = 0; j < 4; ++j) {
    acc0[j] = (floatx4)(0.f); acc1[j] = (floatx4)(0.f); acc2[j] = (floatx4)(0.f);
  }
  const ushort_t* qb = qkvv + (size_t)b * N_ * OC_;
#pragma unroll 1
  for (int chunk = 0; chunk < 4; ++chunk) {
    const int n0 = nc * 256 + chunk * 64;
    __syncthreads();
    // --- stage Q,K,V transposed to [ch][tok] (b32 pair-packed writes) ---
#pragma unroll
    for (int j = 0; j < 2; ++j) {
      const int tok0 = 32 * j + 2 * tp;
      const size_t r0 = (size_t)(n0 + tok0) * OC_ + h * 64 + c0;
#pragma unroll
      for (int tt = 0; tt < 3; ++tt) {
        const int off = (tt == 0) ? 0 : (tt == 1 ? 256 : 768);
        short* T = (tt == 0) ? Qt : (tt == 1 ? Kt : Vt);
        short4v a = *(const short4v*)&qb[r0 + off];
        short4v c = *(const short4v*)&qb[r0 + OC_ + off];
#pragma unroll
        for (int i = 0; i < 4; ++i) {
          unsigned int w = (unsigned int)(ushort_t)a[i] |
                           ((unsigned int)(ushort_t)c[i] << 16);
          *(unsigned int*)&T[(c0 + i) * 72 + tok0] = w;
        }
      }
    }
    // --- stage WE tile [p][tok], row-copy (f32 -> bf16) ---
#pragma unroll
    for (int j2 = 0; j2 < 4; ++j2) {
      const int p = (t >> 4) + 16 * j2;
      float4 wv = *(const float4*)&WE[(size_t)p * N_ + n0 + c0];
      short4v s = {f2bf(wv.x), f2bf(wv.y), f2bf(wv.z), f2bf(wv.w)};
      *(short4v*)&Wt[p * 72 + c0] = s;
    }
    __syncthreads();
    // --- MFMA: wave handles d-strip [16w,16w+16) of all three ops ---
#pragma unroll
    for (int ks = 0; ks < 2; ++ks) {
      const int base = ks * 32 + quad * 8;
      short8 af0 = *(const short8*)&Qt[(16 * wave + m16) * 72 + base];
      short8 afV = *(const short8*)&Vt[(16 * wave + m16) * 72 + base];
      short8 bfK[4], bfW[4];
#pragma unroll
      for (int j = 0; j < 4; ++j) {
        bfK[j] = *(const short8*)&Kt[(16 * j + m16) * 72 + base];
        bfW[j] = *(const short8*)&Wt[(16 * j + m16) * 72 + base];
      }
      const short8 afK = bfK[wave];
#pragma unroll
      for (int j = 0; j < 4; ++j) {
        acc0[j] = __builtin_amdgcn_mfma_f32_16x16x32_bf16(af0, bfK[j], acc0[j], 0, 0, 0);
        acc1[j] = __builtin_amdgcn_mfma_f32_16x16x32_bf16(afK, bfW[j], acc1[j], 0, 0, 0);
        acc2[j] = __builtin_amdgcn_mfma_f32_16x16x32_bf16(afV, bfW[j], acc2[j], 0, 0, 0);
      }
    }
  }
  // --- epilogue: atomic accumulate across nc splits ---
  const size_t obase = (size_t)bh * 4096;
#pragma unroll
  for (int j = 0; j < 4; ++j)
#pragma unroll
    for (int r = 0; r < 4; ++r) {
      const int d = 16 * wave + quad * 4 + r;   // row (from A)
      const int cc = 16 * j + m16;              // col (from B)
      atomicAdd(&Sqk[obase + (size_t)d * 64 + cc], acc0[j][r]);
      atomicAdd(&kp [obase + (size_t)cc * 64 + d], acc1[j][r]);  // [p][d]
      atomicAdd(&vp [obase + (size_t)d * 64 + cc], acc2[j][r]);  // [d][p]
    }
}

// ---------------------------------------------------------------------------
// Channel-attn softmax: logits = S_qk * rq[dd] * rk[e] * temp[h], softmax over e.
__global__ __launch_bounds__(256) void k_ca_softmax(float* __restrict__ Sqk,
                                                    const float* __restrict__ rn,
                                                    const float* __restrict__ temp) {
  const int w = threadIdx.x >> 6;
  const int lane = threadIdx.x & 63;
  const int row = blockIdx.x * 4 + w;  // 0..2047 == b*256 + h*64 + dd
  const int b = row >> 8;
  const int rem = row & 255;
  const int h = rem >> 6;
  const float rq = rn[b * 512 + rem];
  const float rk = rn[b * 512 + 256 + h * 64 + lane];
  float l = Sqk[(size_t)row * 64 + lane] * rq * rk * temp[h];
  float m = l;
#pragma unroll
  for (int o = 32; o; o >>= 1) m = fmaxf(m, __shfl_xor(m, o));
  const float e = __expf(l - m);
  float s = e;
#pragma unroll
  for (int o = 32; o; o >>= 1) s += __shfl_xor(s, o);
  Sqk[(size_t)row * 64 + lane] = e / s;
}

// ---------------------------------------------------------------------------
// x_ca[b,n,h*64+d] = sum_e attn[b,h,d,e] * v_ca[n][e]. 64-token tile.
__global__ __launch_bounds__(256) void k_ca_apply(const ushort_t* __restrict__ qkvv,
                                                  const float* __restrict__ attn,
                                                  float* __restrict__ x_ca) {
  __shared__ float Vs[64][68];   // [tok][e]
  __shared__ float As[64][68];   // [d][e]
  const int bh = blockIdx.x;
  const int b = bh >> 2, h = bh & 3;
  const int n0 = blockIdx.y * 64;
  const int t = threadIdx.x;
#pragma unroll
  for (int j = 0; j < 4; ++j) {
    int i4 = t + j * 256;          // float4 index 0..1023
    int row = i4 >> 4;
    int c0 = (i4 & 15) << 2;
    *(float4*)&As[row][c0] = *(const float4*)&attn[(size_t)bh * 4096 + (size_t)i4 * 4];
    short4v v4 = *(const short4v*)&qkvv[(size_t)(b * N_ + n0 + row) * OC_ + 512 + h * 64 + c0];
    Vs[row][c0 + 0] = bf2f((ushort_t)v4[0]);
    Vs[row][c0 + 1] = bf2f((ushort_t)v4[1]);
    Vs[row][c0 + 2] = bf2f((ushort_t)v4[2]);
    Vs[row][c0 + 3] = bf2f((ushort_t)v4[3]);
  }
  __syncthreads();
  const int tm = t & 15;           // token rows tm+16*i
  const int tn = (t >> 4) << 2;    // channel cols
  float acc[4][4] = {};
#pragma unroll
  for (int e0 = 0; e0 < 64; e0 += 4) {
    float4 a4[4], b4[4];
#pragma unroll
    for (int i = 0; i < 4; ++i) a4[i] = *(const float4*)&Vs[tm + 16 * i][e0];
#pragma unroll
    for (int j = 0; j < 4; ++j) b4[j] = *(const float4*)&As[tn + j][e0];
#pragma unroll
    for (int i = 0; i < 4; ++i)
#pragma unroll
      for (int j = 0; j < 4; ++j)
        acc[i][j] += a4[i].x * b4[j].x + a4[i].y * b4[j].y +
                     a4[i].z * b4[j].z + a4[i].w * b4[j].w;
  }
#pragma unroll
  for (int i = 0; i < 4; ++i) {
    float4 v;
    v.x = acc[i][0]; v.y = acc[i][1]; v.z = acc[i][2]; v.w = acc[i][3];
    *(float4*)&x_ca[(size_t)(b * N_ + n0 + tm + 16 * i) * C_ + h * 64 + tn] = v;
  }
}

// ---------------------------------------------------------------------------
// Spatial attention, tiled (kpT in [p][d], vp in [d][p], q from bf16 qkvv).
__global__ __launch_bounds__(256) void k_sa(const ushort_t* __restrict__ qkvv,
                                            const float* __restrict__ kpT,
                                            const float* __restrict__ vp,
                                            const float* __restrict__ bE,
                                            const float* __restrict__ rn,
                                            const float* __restrict__ temp2,
                                            float* __restrict__ x_sa) {
  __shared__ float Qs[64][68];   // [tok][d]; re-used as S [tok][p] after GEMM1
  __shared__ float Ks[64][68];   // [p][d] scaled
  __shared__ float Vs[64][68];   // [d][p] + bE
  const int bh = blockIdx.x;
  const int b = bh >> 2, h = bh & 3;
  const int n0 = blockIdx.y * 64;
  const int t = threadIdx.x;
  const float t2 = temp2[h];
#pragma unroll
  for (int j = 0; j < 4; ++j) {
    int i4 = t + j * 256;
    int row = i4 >> 4;             // p for Ks, d for Vs, tok for Qs
    int c0 = (i4 & 15) << 2;
    float4 kv = *(const float4*)&kpT[(size_t)bh * 4096 + (size_t)i4 * 4];
    float4 vv = *(const float4*)&vp[(size_t)bh * 4096 + (size_t)i4 * 4];
    const float be_r = bE[row];
    Ks[row][c0 + 0] = (kv.x + be_r) * rn[b * 512 + h * 64 + c0 + 0] * t2;
    Ks[row][c0 + 1] = (kv.y + be_r) * rn[b * 512 + h * 64 + c0 + 1] * t2;
    Ks[row][c0 + 2] = (kv.z + be_r) * rn[b * 512 + h * 64 + c0 + 2] * t2;
    Ks[row][c0 + 3] = (kv.w + be_r) * rn[b * 512 + h * 64 + c0 + 3] * t2;
    Vs[row][c0 + 0] = vv.x + bE[c0 + 0];
    Vs[row][c0 + 1] = vv.y + bE[c0 + 1];
    Vs[row][c0 + 2] = vv.z + bE[c0 + 2];
    Vs[row][c0 + 3] = vv.w + bE[c0 + 3];
    short4v q4 = *(const short4v*)&qkvv[(size_t)(b * N_ + n0 + row) * OC_ + h * 64 + c0];
    Qs[row][c0 + 0] = bf2f((ushort_t)q4[0]);
    Qs[row][c0 + 1] = bf2f((ushort_t)q4[1]);
    Qs[row][c0 + 2] = bf2f((ushort_t)q4[2]);
    Qs[row][c0 + 3] = bf2f((ushort_t)q4[3]);
  }
  __syncthreads();
  const int tm = t & 15;           // token rows tm+16*i
  const int tn = (t >> 4) << 2;    // output cols (p in GEMM1, d in GEMM2)
  float acc[4][4] = {};
#pragma unroll
  for (int d0 = 0; d0 < 64; d0 += 4) {
    float4 a4[4], b4[4];
#pragma unroll
    for (int i = 0; i < 4; ++i) a4[i] = *(const float4*)&Qs[tm + 16 * i][d0];
#pragma unroll
    for (int j = 0; j < 4; ++j) b4[j] = *(const float4*)&Ks[tn + j][d0];
#pragma unroll
    for (int i = 0; i < 4; ++i)
#pragma unroll
      for (int j = 0; j < 4; ++j)
        acc[i][j] += a4[i].x * b4[j].x + a4[i].y * b4[j].y +
                     a4[i].z * b4[j].z + a4[i].w * b4[j].w;
  }
  __syncthreads();                 // all Qs reads done; safe to alias
  float(*Ss)[68] = Qs;
#pragma unroll
  for (int i = 0; i < 4; ++i) {
    float4 v;
    v.x = acc[i][0]; v.y = acc[i][1]; v.z = acc[i][2]; v.w = acc[i][3];
    *(float4*)&Ss[tm + 16 * i][tn] = v;
  }
  __syncthreads();
  // softmax: 4 threads per row, 16 elems each
  {
    const int r = t >> 2;
    const int s0 = (t & 3) << 4;
    float4 v0 = *(float4*)&Ss[r][s0 + 0];
    float4 v1 = *(float4*)&Ss[r][s0 + 4];
    float4 v2 = *(float4*)&Ss[r][s0 + 8];
    float4 v3 = *(float4*)&Ss[r][s0 + 12];
    float m = fmaxf(fmaxf(fmaxf(v0.x, v0.y), fmaxf(v0.z, v0.w)),
                    fmaxf(fmaxf(v1.x, v1.y), fmaxf(v1.z, v1.w)));
    m = fmaxf(m, fmaxf(fmaxf(fmaxf(v2.x, v2.y), fmaxf(v2.z, v2.w)),
                       fmaxf(fmaxf(v3.x, v3.y), fmaxf(v3.z, v3.w))));
    m = fmaxf(m, __shfl_xor(m, 1));
    m = fmaxf(m, __shfl_xor(m, 2));
    v0.x = __expf(v0.x - m); v0.y = __expf(v0.y - m);
    v0.z = __expf(v0.z - m); v0.w = __expf(v0.w - m);
    v1.x = __expf(v1.x - m); v1.y = __expf(v1.y - m);
    v1.z = __expf(v1.z - m); v1.w = __expf(v1.w - m);
    v2.x = __expf(v2.x - m); v2.y = __expf(v2.y - m);
    v2.z = __expf(v2.z - m); v2.w = __expf(v2.w - m);
    v3.x = __expf(v3.x - m); v3.y = __expf(v3.y - m);
    v3.z = __expf(v3.z - m); v3.w = __expf(v3.w - m);
    float s = (v0.x + v0.y + v0.z + v0.w) + (v1.x + v1.y + v1.z + v1.w) +
              (v2.x + v2.y + v2.z + v2.w) + (v3.x + v3.y + v3.z + v3.w);
    s += __shfl_xor(s, 1);
    s += __shfl_xor(s, 2);
    const float inv = 1.f / s;
    v0.x *= inv; v0.y *= inv; v0.z *= inv; v0.w *= inv;
    v1.x *= inv; v1.y *= inv; v1.z *= inv; v1.w *= inv;
    v2.x *= inv; v2.y *= inv; v2.z *= inv; v2.w *= inv;
    v3.x *= inv; v3.y *= inv; v3.z *= inv; v3.w *= inv;
    *(float4*)&Ss[r][s0 + 0] = v0;
    *(float4*)&Ss[r][s0 + 4] = v1;
    *(float4*)&Ss[r][s0 + 8] = v2;
    *(float4*)&Ss[r][s0 + 12] = v3;
  }
  __syncthreads();
  float acc2[4][4] = {};
#pragma unroll
  for (int p0 = 0; p0 < 64; p0 += 4) {
    float4 a4[4], b4[4];
#pragma unroll
    for (int i = 0; i < 4; ++i) a4[i] = *(const float4*)&Ss[tm + 16 * i][p0];
#pragma unroll
    for (int j = 0; j < 4; ++j) b4[j] = *(const float4*)&Vs[tn + j][p0];
#pragma unroll
    for (int i = 0; i < 4; ++i)
#pragma unroll
      for (int j = 0; j < 4; ++j)
        acc2[i][j] += a4[i].x * b4[j].x + a4[i].y * b4[j].y +
                      a4[i].z * b4[j].z + a4[i].w * b4[j].w;
  }
#pragma unroll
  for (int i = 0; i < 4; ++i) {
    float4 v;
    v.x = acc2[i][0]; v.y = acc2[i][1]; v.z = acc2[i][2]; v.w = acc2[i][3];
    *(float4*)&x_sa[(size_t)(b * N_ + n0 + tm + 16 * i) * C_ + h * 64 + tn] = v;
  }
}

// ---------------------------------------------------------------------------
extern "C" void kernel_launch(void* const* d_in, const int* in_sizes, int n_in,
                              void* d_out, int out_size, void* d_ws, size_t ws_size,
                              hipStream_t stream) {
  (void)in_sizes; (void)n_in; (void)out_size; (void)ws_size;
  const float* x  = (const float*)d_in[0];
  // d_in[1] = bank (unused by forward)
  const float* Wq = (const float*)d_in[2];
  const float* WE = (const float*)d_in[3];
  const float* bE = (const float*)d_in[4];
  const float* t1 = (const float*)d_in[5];
  const float* t2 = (const float*)d_in[6];
  const float* W1 = (const float*)d_in[7];
  const float* b1 = (const float*)d_in[8];
  const float* W2 = (const float*)d_in[9];
  const float* b2 = (const float*)d_in[10];
  const float* pa = (const float*)d_in[11];
  float* out = (float*)d_out;

  float* ws = (float*)d_ws;
  size_t off = 0;
  float* xsa  = ws + off; off += (size_t)M_ * C_;            //  8,388,608
  float* xca  = ws + off; off += (size_t)M_ * C_;            //  8,388,608
  float* Sqk  = ws + off; off += (size_t)B_ * H_ * D_ * D_;  //    131,072
  float* kp   = ws + off; off += (size_t)B_ * H_ * D_ * P_;  //    131,072 ([p][d])
  float* vp   = ws + off; off += (size_t)B_ * H_ * D_ * P_;  //    131,072 ([d][p])
  float* ssq  = ws + off; off += (size_t)B_ * 512;           //      4,096
  float* rn   = ws + off; off += (size_t)B_ * 512;           //      4,096
  ushort_t* qkvv = (ushort_t*)(ws + off);                    // 33,554,432 shorts

  // Zero the atomically-accumulated buffers (Sqk,kp,vp,ssq are contiguous).
  hipMemsetAsync(Sqk, 0, (size_t)(3 * 131072 + 4096) * sizeof(float), stream);

  k_qkvv_mfma<<<dim3(M_ / 128, OC_ / 128), 256, 0, stream>>>(x, Wq, qkvv);
  k_norms_partial<<<dim3(16, 8), 256, 0, stream>>>(qkvv, ssq);
  k_norms_final<<<16, 256, 0, stream>>>(ssq, rn);
  k_pair_mfma<<<dim3(32, 16), 256, 0, stream>>>(qkvv, WE, Sqk, kp, vp);
  k_ca_softmax<<<512, 256, 0, stream>>>(Sqk, rn, t1);
  k_ca_apply<<<dim3(32, 64), 256, 0, stream>>>(qkvv, Sqk, xca);
  k_sa<<<dim3(32, 64), 256, 0, stream>>>(qkvv, kp, vp, bE, rn, t2, xsa);
  k_out_mfma<<<dim3(M_ / 128, 2), 256, 0, stream>>>(xsa, xca, W1, b1, W2, b2, pa, out);
}

// Round 5
// 323.859 us; speedup vs baseline: 2.6722x; 1.1830x over previous
//
#include <hip/hip_runtime.h>
#include <cstdint>
#include <cstddef>

// Problem constants (fixed by reference)
constexpr int B_ = 8, N_ = 4096, C_ = 256, H_ = 4, D_ = 64, P_ = 64;
constexpr int OC_ = 4 * C_;      // 1024 qkvv channels
constexpr int M_  = B_ * N_;     // 32768 tokens
constexpr int NC_SPLIT = 16;     // k_pair token splits
constexpr int PAIR_ELEMS = 32 * 3 * 4096;  // per-split partial elements

#define DEV_INLINE __device__ __forceinline__

typedef unsigned short ushort_t;
typedef __attribute__((ext_vector_type(8))) short short8;    // 8 bf16 = 4 VGPR
typedef __attribute__((ext_vector_type(4))) short short4v;   // 4 bf16 = 8 B
typedef __attribute__((ext_vector_type(4))) float floatx4;   // MFMA acc

DEV_INLINE short f2bf(float f) {  // RNE f32 -> bf16
  unsigned int u = __builtin_bit_cast(unsigned int, f);
  u += 0x7FFFu + ((u >> 16) & 1u);
  return (short)(u >> 16);
}
DEV_INLINE float bf2f(ushort_t s) {
  return __builtin_bit_cast(float, (unsigned int)s << 16);
}

// ---------------------------------------------------------------------------
// MFMA tile core (f32 A, f32 B): C[128x128] += A[128x256] * Bw[128x256]^T,
// converted to bf16 during LDS staging (stride 72 shorts).
DEV_INLINE void mfma_core(const float* __restrict__ A, const float* __restrict__ Bw,
                          int bm, short* As, short* Bs, floatx4 acc[4][4]) {
  const int t = threadIdx.x;
  const int c4 = t & 15;
  const int lane = t & 63;
  const int wave = t >> 6;
  const int m16 = lane & 15;
  const int quad = lane >> 4;
  const int wm = (wave >> 1) << 6;
  const int wn = (wave & 1) << 6;
  const float4* A4 = (const float4*)A;
  const float4* B4 = (const float4*)Bw;
#pragma unroll 1
  for (int k0 = 0; k0 < 256; k0 += 64) {
    const int kq = k0 >> 2;
    float4 av[8], bv[8];
#pragma unroll
    for (int j = 0; j < 8; ++j) {
      const int r = (t >> 4) + 16 * j;
      av[j] = A4[(size_t)(bm + r) * 64 + kq + c4];
      bv[j] = B4[(size_t)r * 64 + kq + c4];
    }
    __syncthreads();
#pragma unroll
    for (int j = 0; j < 8; ++j) {
      const int r = (t >> 4) + 16 * j;
      short4v a4s = {f2bf(av[j].x), f2bf(av[j].y), f2bf(av[j].z), f2bf(av[j].w)};
      short4v b4s = {f2bf(bv[j].x), f2bf(bv[j].y), f2bf(bv[j].z), f2bf(bv[j].w)};
      *(short4v*)&As[r * 72 + c4 * 4] = a4s;
      *(short4v*)&Bs[r * 72 + c4 * 4] = b4s;
    }
    __syncthreads();
#pragma unroll
    for (int ks = 0; ks < 2; ++ks) {
      short8 af[4], bf[4];
#pragma unroll
      for (int i = 0; i < 4; ++i)
        af[i] = *(const short8*)&As[(wm + i * 16 + m16) * 72 + ks * 32 + quad * 8];
#pragma unroll
      for (int j = 0; j < 4; ++j)
        bf[j] = *(const short8*)&Bs[(wn + j * 16 + m16) * 72 + ks * 32 + quad * 8];
#pragma unroll
      for (int i = 0; i < 4; ++i)
#pragma unroll
        for (int j = 0; j < 4; ++j)
          acc[i][j] = __builtin_amdgcn_mfma_f32_16x16x32_bf16(af[i], bf[j], acc[i][j], 0, 0, 0);
    }
  }
}

// ---------------------------------------------------------------------------
// qkvv = x @ W_qkvv^T : [32768,256] x [1024,256]^T -> [32768,1024], bf16 out
__global__ __launch_bounds__(256) void k_qkvv_mfma(const float* __restrict__ x,
                                                   const float* __restrict__ W,
                                                   ushort_t* __restrict__ outb) {
  __shared__ __align__(16) short As[128 * 72];
  __shared__ __align__(16) short Bs[128 * 72];
  const int bm = blockIdx.x * 128;
  const int bo = blockIdx.y * 128;
  floatx4 acc[4][4];
#pragma unroll
  for (int i = 0; i < 4; ++i)
#pragma unroll
    for (int j = 0; j < 4; ++j) acc[i][j] = (floatx4)(0.f);
  mfma_core(x, W + (size_t)bo * 256, bm, As, Bs, acc);
  const int lane = threadIdx.x & 63, wave = threadIdx.x >> 6;
  const int m16 = lane & 15, quad = lane >> 4;
  const int wm = (wave >> 1) << 6, wn = (wave & 1) << 6;
#pragma unroll
  for (int i = 0; i < 4; ++i)
#pragma unroll
    for (int r = 0; r < 4; ++r) {
      const int gr = bm + wm + i * 16 + quad * 4 + r;
#pragma unroll
      for (int j = 0; j < 4; ++j)
        outb[(size_t)gr * OC_ + bo + wn + j * 16 + m16] = (ushort_t)f2bf(acc[i][j][r]);
    }
}

// ---------------------------------------------------------------------------
// out[:, half*128 + 0:128] = PReLU(A @ W^T + bias); A is bf16 [M][256].
__global__ __launch_bounds__(256) void k_out_mfma(const ushort_t* __restrict__ xsa,
                                                  const ushort_t* __restrict__ xca,
                                                  const float* __restrict__ W1,
                                                  const float* __restrict__ b1,
                                                  const float* __restrict__ W2,
                                                  const float* __restrict__ b2,
                                                  const float* __restrict__ pa,
                                                  float* __restrict__ out) {
  __shared__ __align__(16) short As[128 * 72];
  __shared__ __align__(16) short Bs[128 * 72];
  const int bm = blockIdx.x * 128;
  const int half = blockIdx.y;
  const ushort_t* A = half ? xca : xsa;
  const float* W = half ? W2 : W1;
  const float* bias = half ? b2 : b1;
  const int t = threadIdx.x;
  const int c4 = t & 15;
  const int oc = t & 7;
  const int lane = t & 63, wave = t >> 6;
  const int m16 = lane & 15, quad = lane >> 4;
  const int wm = (wave >> 1) << 6, wn = (wave & 1) << 6;
  floatx4 acc[4][4];
#pragma unroll
  for (int i = 0; i < 4; ++i)
#pragma unroll
    for (int j = 0; j < 4; ++j) acc[i][j] = (floatx4)(0.f);
  const float4* B4 = (const float4*)W;
#pragma unroll 1
  for (int k0 = 0; k0 < 256; k0 += 64) {
    const int kq = k0 >> 2;
    short8 a8[4];
    float4 bv[8];
#pragma unroll
    for (int j = 0; j < 4; ++j) {
      const int r = (t >> 3) + 32 * j;
      a8[j] = *(const short8*)&A[(size_t)(bm + r) * 256 + k0 + 8 * oc];
    }
#pragma unroll
    for (int j = 0; j < 8; ++j) {
      const int r = (t >> 4) + 16 * j;
      bv[j] = B4[(size_t)r * 64 + kq + c4];
    }
    __syncthreads();
#pragma unroll
    for (int j = 0; j < 4; ++j) {
      const int r = (t >> 3) + 32 * j;
      *(short8*)&As[r * 72 + 8 * oc] = a8[j];
    }
#pragma unroll
    for (int j = 0; j < 8; ++j) {
      const int r = (t >> 4) + 16 * j;
      short4v b4s = {f2bf(bv[j].x), f2bf(bv[j].y), f2bf(bv[j].z), f2bf(bv[j].w)};
      *(short4v*)&Bs[r * 72 + c4 * 4] = b4s;
    }
    __syncthreads();
#pragma unroll
    for (int ks = 0; ks < 2; ++ks) {
      short8 af[4], bf[4];
#pragma unroll
      for (int i = 0; i < 4; ++i)
        af[i] = *(const short8*)&As[(wm + i * 16 + m16) * 72 + ks * 32 + quad * 8];
#pragma unroll
      for (int j = 0; j < 4; ++j)
        bf[j] = *(const short8*)&Bs[(wn + j * 16 + m16) * 72 + ks * 32 + quad * 8];
#pragma unroll
      for (int i = 0; i < 4; ++i)
#pragma unroll
        for (int j = 0; j < 4; ++j)
          acc[i][j] = __builtin_amdgcn_mfma_f32_16x16x32_bf16(af[i], bf[j], acc[i][j], 0, 0, 0);
    }
  }
  const float slope = pa[0];
  float bj[4];
#pragma unroll
  for (int j = 0; j < 4; ++j) bj[j] = bias[wn + j * 16 + m16];
#pragma unroll
  for (int i = 0; i < 4; ++i)
#pragma unroll
    for (int r = 0; r < 4; ++r) {
      const int gr = bm + wm + i * 16 + quad * 4 + r;
#pragma unroll
      for (int j = 0; j < 4; ++j) {
        float v = acc[i][j][r] + bj[j];
        v = v >= 0.f ? v : slope * v;
        out[(size_t)gr * C_ + half * 128 + wn + j * 16 + m16] = v;
      }
    }
}

// ---------------------------------------------------------------------------
// Token-axis sum-of-squares for q (channels 0..255) and k (channels 256..511).
__global__ __launch_bounds__(256) void k_norms_partial(const ushort_t* __restrict__ qkvv,
                                                       float* __restrict__ ssq) {
  const int g = blockIdx.x;           // b*2 + half
  const int b = g >> 1, half = g & 1;
  const int n0 = blockIdx.y * 512;
  const int c = threadIdx.x;          // 0..255
  const ushort_t* p = qkvv + (size_t)b * N_ * OC_ + half * 256 + c;
  float ss = 0.f;
  for (int n = 0; n < 512; ++n) {
    float v = bf2f(p[(size_t)(n0 + n) * OC_]);
    ss += v * v;
  }
  atomicAdd(&ssq[(size_t)b * 512 + half * 256 + c], ss);
}

__global__ void k_norms_final(const float* __restrict__ ssq, float* __restrict__ rn) {
  const int i = blockIdx.x * 256 + threadIdx.x;  // 4096
  rn[i] = 1.f / fmaxf(sqrtf(ssq[i]), 1e-12f);
}

// ---------------------------------------------------------------------------
// Fused per-(b,h) contractions over tokens, MFMA + partial-buffer version.
//   op0: Sqk[d][e] += sum_n Q[n][d] K[n][e]
//   op1: kp [p][d] += sum_n K[n][d] WE[p][n]   (stored transposed for k_sa)
//   op2: vp [d][p] += sum_n V[n][d] WE[p][n]
// LDS tiles [row][tok] bf16, stride 64, XOR octet swizzle col^=8*(row>>3)
// -> staging writes and fragment reads are <=2-way (free).
// Grid (bh=32, nc=16); partials to pp[nc][bh][3][4096], no atomics.
__global__ __launch_bounds__(256) void k_pair_mfma(const ushort_t* __restrict__ qkvv,
                                                   const float* __restrict__ WE,
                                                   float* __restrict__ pp) {
  __shared__ __align__(16) short Qt[64 * 64];
  __shared__ __align__(16) short Kt[64 * 64];
  __shared__ __align__(16) short Vt[64 * 64];
  __shared__ __align__(16) short Wt[64 * 64];
  const int bh = blockIdx.x;
  const int nc = blockIdx.y;
  const int b = bh >> 2, h = bh & 3;
  const int t = threadIdx.x;
  const int lane = t & 63, wave = t >> 6;
  const int m16 = lane & 15, quad = lane >> 4;
  const int c0 = (t & 15) << 2;    // channel quad for staging
  const int tp = t >> 4;           // 0..15
  floatx4 acc0[4], acc1[4], acc2[4];
#pragma unroll
  for (int j = 0; j < 4; ++j) {
    acc0[j] = (floatx4)(0.f); acc1[j] = (floatx4)(0.f); acc2[j] = (floatx4)(0.f);
  }
  const ushort_t* qb = qkvv + (size_t)b * N_ * OC_;
#pragma unroll 1
  for (int chunk = 0; chunk < 4; ++chunk) {
    const int n0 = nc * 256 + chunk * 64;
    __syncthreads();
    // --- stage Q,K,V transposed to [ch][tok], pair-packed u32, swizzled ---
#pragma unroll
    for (int j = 0; j < 2; ++j) {
      const int tok0 = 32 * j + 2 * tp;
      const size_t r0 = (size_t)(n0 + tok0) * OC_ + h * 64 + c0;
#pragma unroll
      for (int tt = 0; tt < 3; ++tt) {
        const int off = (tt == 0) ? 0 : (tt == 1 ? 256 : 768);
        short* T = (tt == 0) ? Qt : (tt == 1 ? Kt : Vt);
        short4v a = *(const short4v*)&qb[r0 + off];
        short4v c = *(const short4v*)&qb[r0 + OC_ + off];
#pragma unroll
        for (int i = 0; i < 4; ++i) {
          const int r = c0 + i;
          const int col = tok0 ^ (8 * (r >> 3));
          unsigned int w = (unsigned int)(ushort_t)a[i] |
                           ((unsigned int)(ushort_t)c[i] << 16);
          *(unsigned int*)&T[r * 64 + col] = w;
        }
      }
    }
    // --- stage WE tile [p][tok] row-copy (f32 -> bf16), swizzled ---
#pragma unroll
    for (int j2 = 0; j2 < 4; ++j2) {
      const int p = tp + 16 * j2;
      float4 wv = *(const float4*)&WE[(size_t)p * N_ + n0 + c0];
      short4v s = {f2bf(wv.x), f2bf(wv.y), f2bf(wv.z), f2bf(wv.w)};
      *(short4v*)&Wt[p * 64 + (c0 ^ (8 * (p >> 3)))] = s;
    }
    __syncthreads();
    // --- MFMA: wave handles d-strip [16*wave, 16*wave+16) of all 3 ops ---
#pragma unroll
    for (int ks = 0; ks < 2; ++ks) {
      const int boct = ks * 32 + quad * 8;
      const int rA = 16 * wave + m16;
      const int swA = boct ^ (8 * (rA >> 3));
      short8 af0 = *(const short8*)&Qt[rA * 64 + swA];
      short8 afK = *(const short8*)&Kt[rA * 64 + swA];
      short8 afV = *(const short8*)&Vt[rA * 64 + swA];
      short8 bfK[4], bfW[4];
#pragma unroll
      for (int j = 0; j < 4; ++j) {
        const int rB = 16 * j + m16;
        const int swB = boct ^ (8 * (rB >> 3));
        bfK[j] = *(const short8*)&Kt[rB * 64 + swB];
        bfW[j] = *(const short8*)&Wt[rB * 64 + swB];
      }
#pragma unroll
      for (int j = 0; j < 4; ++j) {
        acc0[j] = __builtin_amdgcn_mfma_f32_16x16x32_bf16(af0, bfK[j], acc0[j], 0, 0, 0);
        acc1[j] = __builtin_amdgcn_mfma_f32_16x16x32_bf16(afK, bfW[j], acc1[j], 0, 0, 0);
        acc2[j] = __builtin_amdgcn_mfma_f32_16x16x32_bf16(afV, bfW[j], acc2[j], 0, 0, 0);
      }
    }
  }
  // --- epilogue: coalesced partial stores (no atomics) ---
  float* pb = pp + ((size_t)nc * 32 + bh) * (3 * 4096);
#pragma unroll
  for (int j = 0; j < 4; ++j)
#pragma unroll
    for (int r = 0; r < 4; ++r) {
      const int d = 16 * wave + quad * 4 + r;   // row (from A)
      const int cc = 16 * j + m16;              // col (from B)
      pb[0 * 4096 + d * 64 + cc] = acc0[j][r];
      pb[1 * 4096 + cc * 64 + d] = acc1[j][r];  // kp stored [p][d]
      pb[2 * 4096 + d * 64 + cc] = acc2[j][r];  // vp stored [d][p]
    }
}

// Reduce 16 nc-splits: Sqk/kp/vp[bh*4096+idx] = sum_nc pp[nc][bh][op][idx]
__global__ __launch_bounds__(256) void k_pair_reduce(const float* __restrict__ pp,
                                                     float* __restrict__ Sqk,
                                                     float* __restrict__ kp,
                                                     float* __restrict__ vp) {
  const int e = blockIdx.x * 256 + threadIdx.x;   // < 393216
  float s = 0.f;
#pragma unroll
  for (int nc = 0; nc < NC_SPLIT; ++nc) s += pp[(size_t)nc * PAIR_ELEMS + e];
  const int bh = e / 12288;
  const int rem = e - bh * 12288;
  const int op = rem >> 12;
  const int idx = rem & 4095;
  float* dst = (op == 0) ? Sqk : (op == 1 ? kp : vp);
  dst[(size_t)bh * 4096 + idx] = s;
}

// ---------------------------------------------------------------------------
// Channel-attn softmax: logits = S_qk * rq[dd] * rk[e] * temp[h], softmax over e.
__global__ __launch_bounds__(256) void k_ca_softmax(float* __restrict__ Sqk,
                                                    const float* __restrict__ rn,
                                                    const float* __restrict__ temp) {
  const int w = threadIdx.x >> 6;
  const int lane = threadIdx.x & 63;
  const int row = blockIdx.x * 4 + w;  // 0..2047 == b*256 + h*64 + dd
  const int b = row >> 8;
  const int rem = row & 255;
  const int h = rem >> 6;
  const float rq = rn[b * 512 + rem];
  const float rk = rn[b * 512 + 256 + h * 64 + lane];
  float l = Sqk[(size_t)row * 64 + lane] * rq * rk * temp[h];
  float m = l;
#pragma unroll
  for (int o = 32; o; o >>= 1) m = fmaxf(m, __shfl_xor(m, o));
  const float e = __expf(l - m);
  float s = e;
#pragma unroll
  for (int o = 32; o; o >>= 1) s += __shfl_xor(s, o);
  Sqk[(size_t)row * 64 + lane] = e / s;
}

// ---------------------------------------------------------------------------
// x_ca[b,n,h*64+d] = sum_e attn[b,h,d,e] * v_ca[n][e]. 64-token tile. bf16 out.
__global__ __launch_bounds__(256) void k_ca_apply(const ushort_t* __restrict__ qkvv,
                                                  const float* __restrict__ attn,
                                                  ushort_t* __restrict__ x_ca) {
  __shared__ float Vs[64][68];   // [tok][e]
  __shared__ float As[64][68];   // [d][e]
  const int bh = blockIdx.x;
  const int b = bh >> 2, h = bh & 3;
  const int n0 = blockIdx.y * 64;
  const int t = threadIdx.x;
#pragma unroll
  for (int j = 0; j < 4; ++j) {
    int i4 = t + j * 256;          // float4 index 0..1023
    int row = i4 >> 4;
    int c0 = (i4 & 15) << 2;
    *(float4*)&As[row][c0] = *(const float4*)&attn[(size_t)bh * 4096 + (size_t)i4 * 4];
    short4v v4 = *(const short4v*)&qkvv[(size_t)(b * N_ + n0 + row) * OC_ + 512 + h * 64 + c0];
    Vs[row][c0 + 0] = bf2f((ushort_t)v4[0]);
    Vs[row][c0 + 1] = bf2f((ushort_t)v4[1]);
    Vs[row][c0 + 2] = bf2f((ushort_t)v4[2]);
    Vs[row][c0 + 3] = bf2f((ushort_t)v4[3]);
  }
  __syncthreads();
  const int tm = t & 15;           // token rows tm+16*i
  const int tn = (t >> 4) << 2;    // channel cols
  float acc[4][4] = {};
#pragma unroll
  for (int e0 = 0; e0 < 64; e0 += 4) {
    float4 a4[4], b4[4];
#pragma unroll
    for (int i = 0; i < 4; ++i) a4[i] = *(const float4*)&Vs[tm + 16 * i][e0];
#pragma unroll
    for (int j = 0; j < 4; ++j) b4[j] = *(const float4*)&As[tn + j][e0];
#pragma unroll
    for (int i = 0; i < 4; ++i)
#pragma unroll
      for (int j = 0; j < 4; ++j)
        acc[i][j] += a4[i].x * b4[j].x + a4[i].y * b4[j].y +
                     a4[i].z * b4[j].z + a4[i].w * b4[j].w;
  }
#pragma unroll
  for (int i = 0; i < 4; ++i) {
    short4v v = {f2bf(acc[i][0]), f2bf(acc[i][1]), f2bf(acc[i][2]), f2bf(acc[i][3])};
    *(short4v*)&x_ca[(size_t)(b * N_ + n0 + tm + 16 * i) * C_ + h * 64 + tn] = v;
  }
}

// ---------------------------------------------------------------------------
// Spatial attention, tiled (kpT in [p][d], vp in [d][p], q from bf16 qkvv). bf16 out.
__global__ __launch_bounds__(256) void k_sa(const ushort_t* __restrict__ qkvv,
                                            const float* __restrict__ kpT,
                                            const float* __restrict__ vp,
                                            const float* __restrict__ bE,
                                            const float* __restrict__ rn,
                                            const float* __restrict__ temp2,
                                            ushort_t* __restrict__ x_sa) {
  __shared__ float Qs[64][68];   // [tok][d]; re-used as S [tok][p] after GEMM1
  __shared__ float Ks[64][68];   // [p][d] scaled
  __shared__ float Vs[64][68];   // [d][p] + bE
  const int bh = blockIdx.x;
  const int b = bh >> 2, h = bh & 3;
  const int n0 = blockIdx.y * 64;
  const int t = threadIdx.x;
  const float t2 = temp2[h];
#pragma unroll
  for (int j = 0; j < 4; ++j) {
    int i4 = t + j * 256;
    int row = i4 >> 4;             // p for Ks, d for Vs, tok for Qs
    int c0 = (i4 & 15) << 2;
    float4 kv = *(const float4*)&kpT[(size_t)bh * 4096 + (size_t)i4 * 4];
    float4 vv = *(const float4*)&vp[(size_t)bh * 4096 + (size_t)i4 * 4];
    const float be_r = bE[row];
    Ks[row][c0 + 0] = (kv.x + be_r) * rn[b * 512 + h * 64 + c0 + 0] * t2;
    Ks[row][c0 + 1] = (kv.y + be_r) * rn[b * 512 + h * 64 + c0 + 1] * t2;
    Ks[row][c0 + 2] = (kv.z + be_r) * rn[b * 512 + h * 64 + c0 + 2] * t2;
    Ks[row][c0 + 3] = (kv.w + be_r) * rn[b * 512 + h * 64 + c0 + 3] * t2;
    Vs[row][c0 + 0] = vv.x + bE[c0 + 0];
    Vs[row][c0 + 1] = vv.y + bE[c0 + 1];
    Vs[row][c0 + 2] = vv.z + bE[c0 + 2];
    Vs[row][c0 + 3] = vv.w + bE[c0 + 3];
    short4v q4 = *(const short4v*)&qkvv[(size_t)(b * N_ + n0 + row) * OC_ + h * 64 + c0];
    Qs[row][c0 + 0] = bf2f((ushort_t)q4[0]);
    Qs[row][c0 + 1] = bf2f((ushort_t)q4[1]);
    Qs[row][c0 + 2] = bf2f((ushort_t)q4[2]);
    Qs[row][c0 + 3] = bf2f((ushort_t)q4[3]);
  }
  __syncthreads();
  const int tm = t & 15;           // token rows tm+16*i
  const int tn = (t >> 4) << 2;    // output cols (p in GEMM1, d in GEMM2)
  float acc[4][4] = {};
#pragma unroll
  for (int d0 = 0; d0 < 64; d0 += 4) {
    float4 a4[4], b4[4];
#pragma unroll
    for (int i = 0; i < 4; ++i) a4[i] = *(const float4*)&Qs[tm + 16 * i][d0];
#pragma unroll
    for (int j = 0; j < 4; ++j) b4[j] = *(const float4*)&Ks[tn + j][d0];
#pragma unroll
    for (int i = 0; i < 4; ++i)
#pragma unroll
      for (int j = 0; j < 4; ++j)
        acc[i][j] += a4[i].x * b4[j].x + a4[i].y * b4[j].y +
                     a4[i].z * b4[j].z + a4[i].w * b4[j].w;
  }
  __syncthreads();                 // all Qs reads done; safe to alias
  float(*Ss)[68] = Qs;
#pragma unroll
  for (int i = 0; i < 4; ++i) {
    float4 v;
    v.x = acc[i][0]; v.y = acc[i][1]; v.z = acc[i][2]; v.w = acc[i][3];
    *(float4*)&Ss[tm + 16 * i][tn] = v;
  }
  __syncthreads();
  // softmax: 4 threads per row, 16 elems each
  {
    const int r = t >> 2;
    const int s0 = (t & 3) << 4;
    float4 v0 = *(float4*)&Ss[r][s0 + 0];
    float4 v1 = *(float4*)&Ss[r][s0 + 4];
    float4 v2 = *(float4*)&Ss[r][s0 + 8];
    float4 v3 = *(float4*)&Ss[r][s0 + 12];
    float m = fmaxf(fmaxf(fmaxf(v0.x, v0.y), fmaxf(v0.z, v0.w)),
                    fmaxf(fmaxf(v1.x, v1.y), fmaxf(v1.z, v1.w)));
    m = fmaxf(m, fmaxf(fmaxf(fmaxf(v2.x, v2.y), fmaxf(v2.z, v2.w)),
                       fmaxf(fmaxf(v3.x, v3.y), fmaxf(v3.z, v3.w))));
    m = fmaxf(m, __shfl_xor(m, 1));
    m = fmaxf(m, __shfl_xor(m, 2));
    v0.x = __expf(v0.x - m); v0.y = __expf(v0.y - m);
    v0.z = __expf(v0.z - m); v0.w = __expf(v0.w - m);
    v1.x = __expf(v1.x - m); v1.y = __expf(v1.y - m);
    v1.z = __expf(v1.z - m); v1.w = __expf(v1.w - m);
    v2.x = __expf(v2.x - m); v2.y = __expf(v2.y - m);
    v2.z = __expf(v2.z - m); v2.w = __expf(v2.w - m);
    v3.x = __expf(v3.x - m); v3.y = __expf(v3.y - m);
    v3.z = __expf(v3.z - m); v3.w = __expf(v3.w - m);
    float s = (v0.x + v0.y + v0.z + v0.w) + (v1.x + v1.y + v1.z + v1.w) +
              (v2.x + v2.y + v2.z + v2.w) + (v3.x + v3.y + v3.z + v3.w);
    s += __shfl_xor(s, 1);
    s += __shfl_xor(s, 2);
    const float inv = 1.f / s;
    v0.x *= inv; v0.y *= inv; v0.z *= inv; v0.w *= inv;
    v1.x *= inv; v1.y *= inv; v1.z *= inv; v1.w *= inv;
    v2.x *= inv; v2.y *= inv; v2.z *= inv; v2.w *= inv;
    v3.x *= inv; v3.y *= inv; v3.z *= inv; v3.w *= inv;
    *(float4*)&Ss[r][s0 + 0] = v0;
    *(float4*)&Ss[r][s0 + 4] = v1;
    *(float4*)&Ss[r][s0 + 8] = v2;
    *(float4*)&Ss[r][s0 + 12] = v3;
  }
  __syncthreads();
  float acc2[4][4] = {};
#pragma unroll
  for (int p0 = 0; p0 < 64; p0 += 4) {
    float4 a4[4], b4[4];
#pragma unroll
    for (int i = 0; i < 4; ++i) a4[i] = *(const float4*)&Ss[tm + 16 * i][p0];
#pragma unroll
    for (int j = 0; j < 4; ++j) b4[j] = *(const float4*)&Vs[tn + j][p0];
#pragma unroll
    for (int i = 0; i < 4; ++i)
#pragma unroll
      for (int j = 0; j < 4; ++j)
        acc2[i][j] += a4[i].x * b4[j].x + a4[i].y * b4[j].y +
                      a4[i].z * b4[j].z + a4[i].w * b4[j].w;
  }
#pragma unroll
  for (int i = 0; i < 4; ++i) {
    short4v v = {f2bf(acc2[i][0]), f2bf(acc2[i][1]), f2bf(acc2[i][2]), f2bf(acc2[i][3])};
    *(short4v*)&x_sa[(size_t)(b * N_ + n0 + tm + 16 * i) * C_ + h * 64 + tn] = v;
  }
}

// ---------------------------------------------------------------------------
extern "C" void kernel_launch(void* const* d_in, const int* in_sizes, int n_in,
                              void* d_out, int out_size, void* d_ws, size_t ws_size,
                              hipStream_t stream) {
  (void)in_sizes; (void)n_in; (void)out_size; (void)ws_size;
  const float* x  = (const float*)d_in[0];
  // d_in[1] = bank (unused by forward)
  const float* Wq = (const float*)d_in[2];
  const float* WE = (const float*)d_in[3];
  const float* bE = (const float*)d_in[4];
  const float* t1 = (const float*)d_in[5];
  const float* t2 = (const float*)d_in[6];
  const float* W1 = (const float*)d_in[7];
  const float* b1 = (const float*)d_in[8];
  const float* W2 = (const float*)d_in[9];
  const float* b2 = (const float*)d_in[10];
  const float* pa = (const float*)d_in[11];
  float* out = (float*)d_out;

  float* ws = (float*)d_ws;
  size_t off = 0;
  float* Sqk  = ws + off; off += (size_t)B_ * H_ * D_ * D_;  //    131,072
  float* kp   = ws + off; off += (size_t)B_ * H_ * D_ * P_;  //    131,072 ([p][d])
  float* vp   = ws + off; off += (size_t)B_ * H_ * D_ * P_;  //    131,072 ([d][p])
  float* ssq  = ws + off; off += (size_t)B_ * 512;           //      4,096
  float* rn   = ws + off; off += (size_t)B_ * 512;           //      4,096
  float* pp   = ws + off; off += (size_t)NC_SPLIT * PAIR_ELEMS;  // 6,291,456
  ushort_t* qkvv = (ushort_t*)(ws + off); off += (size_t)M_ * OC_ / 2;  // bf16
  ushort_t* xsa  = (ushort_t*)(ws + off); off += (size_t)M_ * C_ / 2;   // bf16
  ushort_t* xca  = (ushort_t*)(ws + off); off += (size_t)M_ * C_ / 2;   // bf16

  // Only ssq is atomically accumulated now.
  hipMemsetAsync(ssq, 0, 4096 * sizeof(float), stream);

  k_qkvv_mfma<<<dim3(M_ / 128, OC_ / 128), 256, 0, stream>>>(x, Wq, qkvv);
  k_norms_partial<<<dim3(16, 8), 256, 0, stream>>>(qkvv, ssq);
  k_norms_final<<<16, 256, 0, stream>>>(ssq, rn);
  k_pair_mfma<<<dim3(32, NC_SPLIT), 256, 0, stream>>>(qkvv, WE, pp);
  k_pair_reduce<<<PAIR_ELEMS / 256, 256, 0, stream>>>(pp, Sqk, kp, vp);
  k_ca_softmax<<<512, 256, 0, stream>>>(Sqk, rn, t1);
  k_ca_apply<<<dim3(32, 64), 256, 0, stream>>>(qkvv, Sqk, xca);
  k_sa<<<dim3(32, 64), 256, 0, stream>>>(qkvv, kp, vp, bE, rn, t2, xsa);
  k_out_mfma<<<dim3(M_ / 128, 2), 256, 0, stream>>>(xsa, xca, W1, b1, W2, b2, pa, out);
}

// Round 6
// 236.474 us; speedup vs baseline: 3.6596x; 1.3695x over previous
//
#include <hip/hip_runtime.h>
#include <cstdint>
#include <cstddef>

// Problem constants (fixed by reference)
constexpr int B_ = 8, N_ = 4096, C_ = 256, H_ = 4, D_ = 64, P_ = 64;
constexpr int OC_ = 4 * C_;      // 1024 qkvv channels
constexpr int M_  = B_ * N_;     // 32768 tokens
constexpr int NC_SPLIT = 16;     // k_pair token splits
constexpr int PAIR_ELEMS = 32 * 3 * 4096;  // per-split partial elements

#define DEV_INLINE __device__ __forceinline__

typedef unsigned short ushort_t;
typedef __attribute__((ext_vector_type(8))) short short8;    // 8 bf16 = 4 VGPR
typedef __attribute__((ext_vector_type(4))) short short4v;   // 4 bf16 = 8 B
typedef __attribute__((ext_vector_type(4))) float floatx4;   // MFMA acc

DEV_INLINE short f2bf(float f) {  // RNE f32 -> bf16
  unsigned int u = __builtin_bit_cast(unsigned int, f);
  u += 0x7FFFu + ((u >> 16) & 1u);
  return (short)(u >> 16);
}
DEV_INLINE float bf2f(ushort_t s) {
  return __builtin_bit_cast(float, (unsigned int)s << 16);
}

// ---------------------------------------------------------------------------
// MFMA tile core (f32 A, f32 B): C[128x128] += A[128x256] * Bw[128x256]^T,
// converted to bf16 during LDS staging (stride 72 shorts).
DEV_INLINE void mfma_core(const float* __restrict__ A, const float* __restrict__ Bw,
                          int bm, short* As, short* Bs, floatx4 acc[4][4]) {
  const int t = threadIdx.x;
  const int c4 = t & 15;
  const int lane = t & 63;
  const int wave = t >> 6;
  const int m16 = lane & 15;
  const int quad = lane >> 4;
  const int wm = (wave >> 1) << 6;
  const int wn = (wave & 1) << 6;
  const float4* A4 = (const float4*)A;
  const float4* B4 = (const float4*)Bw;
#pragma unroll 1
  for (int k0 = 0; k0 < 256; k0 += 64) {
    const int kq = k0 >> 2;
    float4 av[8], bv[8];
#pragma unroll
    for (int j = 0; j < 8; ++j) {
      const int r = (t >> 4) + 16 * j;
      av[j] = A4[(size_t)(bm + r) * 64 + kq + c4];
      bv[j] = B4[(size_t)r * 64 + kq + c4];
    }
    __syncthreads();
#pragma unroll
    for (int j = 0; j < 8; ++j) {
      const int r = (t >> 4) + 16 * j;
      short4v a4s = {f2bf(av[j].x), f2bf(av[j].y), f2bf(av[j].z), f2bf(av[j].w)};
      short4v b4s = {f2bf(bv[j].x), f2bf(bv[j].y), f2bf(bv[j].z), f2bf(bv[j].w)};
      *(short4v*)&As[r * 72 + c4 * 4] = a4s;
      *(short4v*)&Bs[r * 72 + c4 * 4] = b4s;
    }
    __syncthreads();
#pragma unroll
    for (int ks = 0; ks < 2; ++ks) {
      short8 af[4], bf[4];
#pragma unroll
      for (int i = 0; i < 4; ++i)
        af[i] = *(const short8*)&As[(wm + i * 16 + m16) * 72 + ks * 32 + quad * 8];
#pragma unroll
      for (int j = 0; j < 4; ++j)
        bf[j] = *(const short8*)&Bs[(wn + j * 16 + m16) * 72 + ks * 32 + quad * 8];
#pragma unroll
      for (int i = 0; i < 4; ++i)
#pragma unroll
        for (int j = 0; j < 4; ++j)
          acc[i][j] = __builtin_amdgcn_mfma_f32_16x16x32_bf16(af[i], bf[j], acc[i][j], 0, 0, 0);
    }
  }
}

// ---------------------------------------------------------------------------
// qkvv = x @ W_qkvv^T -> bf16 [32768,1024]; also accumulates token-axis
// sum-of-squares for channels 0..511 (q,k) into ssq from the f32 accumulators.
__global__ __launch_bounds__(256) void k_qkvv_mfma(const float* __restrict__ x,
                                                   const float* __restrict__ W,
                                                   ushort_t* __restrict__ outb,
                                                   float* __restrict__ ssq) {
  __shared__ __align__(16) short As[128 * 72];
  __shared__ __align__(16) short Bs[128 * 72];
  const int bm = blockIdx.x * 128;
  const int bo = blockIdx.y * 128;
  floatx4 acc[4][4];
#pragma unroll
  for (int i = 0; i < 4; ++i)
#pragma unroll
    for (int j = 0; j < 4; ++j) acc[i][j] = (floatx4)(0.f);
  mfma_core(x, W + (size_t)bo * 256, bm, As, Bs, acc);
  const int lane = threadIdx.x & 63, wave = threadIdx.x >> 6;
  const int m16 = lane & 15, quad = lane >> 4;
  const int wm = (wave >> 1) << 6, wn = (wave & 1) << 6;
#pragma unroll
  for (int i = 0; i < 4; ++i)
#pragma unroll
    for (int r = 0; r < 4; ++r) {
      const int gr = bm + wm + i * 16 + quad * 4 + r;
#pragma unroll
      for (int j = 0; j < 4; ++j)
        outb[(size_t)gr * OC_ + bo + wn + j * 16 + m16] = (ushort_t)f2bf(acc[i][j][r]);
    }
  if (bo < 512) {  // q,k channels: accumulate sum-of-squares over tokens
    const int b = bm >> 12;
    float sj[4];
#pragma unroll
    for (int j = 0; j < 4; ++j) {
      float s = 0.f;
#pragma unroll
      for (int i = 0; i < 4; ++i)
#pragma unroll
        for (int r = 0; r < 4; ++r) s += acc[i][j][r] * acc[i][j][r];
      s += __shfl_xor(s, 16);
      s += __shfl_xor(s, 32);
      sj[j] = s;
    }
    if (lane < 16) {
#pragma unroll
      for (int j = 0; j < 4; ++j)
        atomicAdd(&ssq[b * 512 + bo + wn + 16 * j + m16], sj[j]);
    }
  }
}

// ---------------------------------------------------------------------------
// out[:, half*128 + 0:128] = PReLU(A @ W^T + bias); A is bf16 [M][256].
__global__ __launch_bounds__(256) void k_out_mfma(const ushort_t* __restrict__ xsa,
                                                  const ushort_t* __restrict__ xca,
                                                  const float* __restrict__ W1,
                                                  const float* __restrict__ b1,
                                                  const float* __restrict__ W2,
                                                  const float* __restrict__ b2,
                                                  const float* __restrict__ pa,
                                                  float* __restrict__ out) {
  __shared__ __align__(16) short As[128 * 72];
  __shared__ __align__(16) short Bs[128 * 72];
  const int bm = blockIdx.x * 128;
  const int half = blockIdx.y;
  const ushort_t* A = half ? xca : xsa;
  const float* W = half ? W2 : W1;
  const float* bias = half ? b2 : b1;
  const int t = threadIdx.x;
  const int c4 = t & 15;
  const int oc = t & 7;
  const int lane = t & 63, wave = t >> 6;
  const int m16 = lane & 15, quad = lane >> 4;
  const int wm = (wave >> 1) << 6, wn = (wave & 1) << 6;
  floatx4 acc[4][4];
#pragma unroll
  for (int i = 0; i < 4; ++i)
#pragma unroll
    for (int j = 0; j < 4; ++j) acc[i][j] = (floatx4)(0.f);
  const float4* B4 = (const float4*)W;
#pragma unroll 1
  for (int k0 = 0; k0 < 256; k0 += 64) {
    const int kq = k0 >> 2;
    short8 a8[4];
    float4 bv[8];
#pragma unroll
    for (int j = 0; j < 4; ++j) {
      const int r = (t >> 3) + 32 * j;
      a8[j] = *(const short8*)&A[(size_t)(bm + r) * 256 + k0 + 8 * oc];
    }
#pragma unroll
    for (int j = 0; j < 8; ++j) {
      const int r = (t >> 4) + 16 * j;
      bv[j] = B4[(size_t)r * 64 + kq + c4];
    }
    __syncthreads();
#pragma unroll
    for (int j = 0; j < 4; ++j) {
      const int r = (t >> 3) + 32 * j;
      *(short8*)&As[r * 72 + 8 * oc] = a8[j];
    }
#pragma unroll
    for (int j = 0; j < 8; ++j) {
      const int r = (t >> 4) + 16 * j;
      short4v b4s = {f2bf(bv[j].x), f2bf(bv[j].y), f2bf(bv[j].z), f2bf(bv[j].w)};
      *(short4v*)&Bs[r * 72 + c4 * 4] = b4s;
    }
    __syncthreads();
#pragma unroll
    for (int ks = 0; ks < 2; ++ks) {
      short8 af[4], bf[4];
#pragma unroll
      for (int i = 0; i < 4; ++i)
        af[i] = *(const short8*)&As[(wm + i * 16 + m16) * 72 + ks * 32 + quad * 8];
#pragma unroll
      for (int j = 0; j < 4; ++j)
        bf[j] = *(const short8*)&Bs[(wn + j * 16 + m16) * 72 + ks * 32 + quad * 8];
#pragma unroll
      for (int i = 0; i < 4; ++i)
#pragma unroll
        for (int j = 0; j < 4; ++j)
          acc[i][j] = __builtin_amdgcn_mfma_f32_16x16x32_bf16(af[i], bf[j], acc[i][j], 0, 0, 0);
    }
  }
  const float slope = pa[0];
  float bj[4];
#pragma unroll
  for (int j = 0; j < 4; ++j) bj[j] = bias[wn + j * 16 + m16];
#pragma unroll
  for (int i = 0; i < 4; ++i)
#pragma unroll
    for (int r = 0; r < 4; ++r) {
      const int gr = bm + wm + i * 16 + quad * 4 + r;
#pragma unroll
      for (int j = 0; j < 4; ++j) {
        float v = acc[i][j][r] + bj[j];
        v = v >= 0.f ? v : slope * v;
        out[(size_t)gr * C_ + half * 128 + wn + j * 16 + m16] = v;
      }
    }
}

__global__ void k_norms_final(const float* __restrict__ ssq, float* __restrict__ rn) {
  const int i = blockIdx.x * 256 + threadIdx.x;  // 4096
  rn[i] = 1.f / fmaxf(sqrtf(ssq[i]), 1e-12f);
}

// ---------------------------------------------------------------------------
// Fused per-(b,h) contractions over tokens, MFMA + partial-buffer version.
__global__ __launch_bounds__(256) void k_pair_mfma(const ushort_t* __restrict__ qkvv,
                                                   const float* __restrict__ WE,
                                                   float* __restrict__ pp) {
  __shared__ __align__(16) short Qt[64 * 64];
  __shared__ __align__(16) short Kt[64 * 64];
  __shared__ __align__(16) short Vt[64 * 64];
  __shared__ __align__(16) short Wt[64 * 64];
  const int bh = blockIdx.x;
  const int nc = blockIdx.y;
  const int b = bh >> 2, h = bh & 3;
  const int t = threadIdx.x;
  const int lane = t & 63, wave = t >> 6;
  const int m16 = lane & 15, quad = lane >> 4;
  const int c0 = (t & 15) << 2;    // channel quad for staging
  const int tp = t >> 4;           // 0..15
  floatx4 acc0[4], acc1[4], acc2[4];
#pragma unroll
  for (int j = 0; j < 4; ++j) {
    acc0[j] = (floatx4)(0.f); acc1[j] = (floatx4)(0.f); acc2[j] = (floatx4)(0.f);
  }
  const ushort_t* qb = qkvv + (size_t)b * N_ * OC_;
#pragma unroll 1
  for (int chunk = 0; chunk < 4; ++chunk) {
    const int n0 = nc * 256 + chunk * 64;
    __syncthreads();
#pragma unroll
    for (int j = 0; j < 2; ++j) {
      const int tok0 = 32 * j + 2 * tp;
      const size_t r0 = (size_t)(n0 + tok0) * OC_ + h * 64 + c0;
#pragma unroll
      for (int tt = 0; tt < 3; ++tt) {
        const int off = (tt == 0) ? 0 : (tt == 1 ? 256 : 768);
        short* T = (tt == 0) ? Qt : (tt == 1 ? Kt : Vt);
        short4v a = *(const short4v*)&qb[r0 + off];
        short4v c = *(const short4v*)&qb[r0 + OC_ + off];
#pragma unroll
        for (int i = 0; i < 4; ++i) {
          const int r = c0 + i;
          const int col = tok0 ^ (8 * (r >> 3));
          unsigned int w = (unsigned int)(ushort_t)a[i] |
                           ((unsigned int)(ushort_t)c[i] << 16);
          *(unsigned int*)&T[r * 64 + col] = w;
        }
      }
    }
#pragma unroll
    for (int j2 = 0; j2 < 4; ++j2) {
      const int p = tp + 16 * j2;
      float4 wv = *(const float4*)&WE[(size_t)p * N_ + n0 + c0];
      short4v s = {f2bf(wv.x), f2bf(wv.y), f2bf(wv.z), f2bf(wv.w)};
      *(short4v*)&Wt[p * 64 + (c0 ^ (8 * (p >> 3)))] = s;
    }
    __syncthreads();
#pragma unroll
    for (int ks = 0; ks < 2; ++ks) {
      const int boct = ks * 32 + quad * 8;
      const int rA = 16 * wave + m16;
      const int swA = boct ^ (8 * (rA >> 3));
      short8 af0 = *(const short8*)&Qt[rA * 64 + swA];
      short8 afK = *(const short8*)&Kt[rA * 64 + swA];
      short8 afV = *(const short8*)&Vt[rA * 64 + swA];
      short8 bfK[4], bfW[4];
#pragma unroll
      for (int j = 0; j < 4; ++j) {
        const int rB = 16 * j + m16;
        const int swB = boct ^ (8 * (rB >> 3));
        bfK[j] = *(const short8*)&Kt[rB * 64 + swB];
        bfW[j] = *(const short8*)&Wt[rB * 64 + swB];
      }
#pragma unroll
      for (int j = 0; j < 4; ++j) {
        acc0[j] = __builtin_amdgcn_mfma_f32_16x16x32_bf16(af0, bfK[j], acc0[j], 0, 0, 0);
        acc1[j] = __builtin_amdgcn_mfma_f32_16x16x32_bf16(afK, bfW[j], acc1[j], 0, 0, 0);
        acc2[j] = __builtin_amdgcn_mfma_f32_16x16x32_bf16(afV, bfW[j], acc2[j], 0, 0, 0);
      }
    }
  }
  float* pb = pp + ((size_t)nc * 32 + bh) * (3 * 4096);
#pragma unroll
  for (int j = 0; j < 4; ++j)
#pragma unroll
    for (int r = 0; r < 4; ++r) {
      const int d = 16 * wave + quad * 4 + r;   // row (from A)
      const int cc = 16 * j + m16;              // col (from B)
      pb[0 * 4096 + d * 64 + cc] = acc0[j][r];
      pb[1 * 4096 + cc * 64 + d] = acc1[j][r];  // kp stored [p][d]
      pb[2 * 4096 + d * 64 + cc] = acc2[j][r];  // vp stored [d][p]
    }
}

// Reduce 16 nc-splits and finalize: Sqk f32; ksb = bf16((kp+bE[p])*rn_q[d]*t2);
// vsb = bf16(vp + bE[p]).
__global__ __launch_bounds__(256) void k_pair_reduce(const float* __restrict__ pp,
                                                     const float* __restrict__ bE,
                                                     const float* __restrict__ rn,
                                                     const float* __restrict__ t2,
                                                     float* __restrict__ Sqk,
                                                     ushort_t* __restrict__ ksb,
                                                     ushort_t* __restrict__ vsb) {
  const int e = blockIdx.x * 256 + threadIdx.x;   // < 393216
  float s = 0.f;
#pragma unroll
  for (int nc = 0; nc < NC_SPLIT; ++nc) s += pp[(size_t)nc * PAIR_ELEMS + e];
  const int bh = e / 12288;
  const int rem = e - bh * 12288;
  const int op = rem >> 12;
  const int idx = rem & 4095;
  const int b = bh >> 2, h = bh & 3;
  if (op == 0) {
    Sqk[(size_t)bh * 4096 + idx] = s;
  } else if (op == 1) {
    const int p = idx >> 6, d = idx & 63;
    ksb[(size_t)bh * 4096 + idx] =
        (ushort_t)f2bf((s + bE[p]) * rn[b * 512 + h * 64 + d] * t2[h]);
  } else {
    const int p = idx & 63;
    vsb[(size_t)bh * 4096 + idx] = (ushort_t)f2bf(s + bE[p]);
  }
}

// ---------------------------------------------------------------------------
// Channel-attn softmax -> bf16 attn [bh][d][e].
__global__ __launch_bounds__(256) void k_ca_softmax(const float* __restrict__ Sqk,
                                                    const float* __restrict__ rn,
                                                    const float* __restrict__ temp,
                                                    ushort_t* __restrict__ ab) {
  const int w = threadIdx.x >> 6;
  const int lane = threadIdx.x & 63;
  const int row = blockIdx.x * 4 + w;  // 0..2047 == b*256 + h*64 + dd
  const int b = row >> 8;
  const int rem = row & 255;
  const int h = rem >> 6;
  const float rq = rn[b * 512 + rem];
  const float rk = rn[b * 512 + 256 + h * 64 + lane];
  float l = Sqk[(size_t)row * 64 + lane] * rq * rk * temp[h];
  float m = l;
#pragma unroll
  for (int o = 32; o; o >>= 1) m = fmaxf(m, __shfl_xor(m, o));
  const float e = __expf(l - m);
  float s = e;
#pragma unroll
  for (int o = 32; o; o >>= 1) s += __shfl_xor(s, o);
  ab[(size_t)row * 64 + lane] = (ushort_t)f2bf(e / s);
}

// ---------------------------------------------------------------------------
// x_ca = attn @ v_ca per (b,h): MFMA, all fragments direct global 16B loads.
// Wave handles 2 groups of 16 tokens; block = 128 tokens. No LDS.
__global__ __launch_bounds__(256) void k_ca_mfma(const ushort_t* __restrict__ qkvv,
                                                 const ushort_t* __restrict__ ab,
                                                 ushort_t* __restrict__ x_ca) {
  const int bh = blockIdx.x;
  const int b = bh >> 2, h = bh & 3;
  const int n0 = blockIdx.y * 128;
  const int lane = threadIdx.x & 63, wave = threadIdx.x >> 6;
  const int m16 = lane & 15, quad = lane >> 4;
  const ushort_t* abb = ab + (size_t)bh * 4096;
  short8 bf[2][4];
#pragma unroll
  for (int ks = 0; ks < 2; ++ks)
#pragma unroll
    for (int j = 0; j < 4; ++j)
      bf[ks][j] = *(const short8*)&abb[(16 * j + m16) * 64 + ks * 32 + quad * 8];
#pragma unroll
  for (int mm = 0; mm < 2; ++mm) {
    const int tokbase = n0 + 64 * mm + 16 * wave;
    const ushort_t* vrow =
        qkvv + (size_t)(b * N_ + tokbase + m16) * OC_ + 512 + h * 64 + quad * 8;
    short8 af0 = *(const short8*)&vrow[0];
    short8 af1 = *(const short8*)&vrow[32];
    floatx4 o[4];
#pragma unroll
    for (int j = 0; j < 4; ++j) o[j] = (floatx4)(0.f);
#pragma unroll
    for (int j = 0; j < 4; ++j) {
      o[j] = __builtin_amdgcn_mfma_f32_16x16x32_bf16(af0, bf[0][j], o[j], 0, 0, 0);
      o[j] = __builtin_amdgcn_mfma_f32_16x16x32_bf16(af1, bf[1][j], o[j], 0, 0, 0);
    }
#pragma unroll
    for (int j = 0; j < 4; ++j)
#pragma unroll
      for (int r = 0; r < 4; ++r)
        x_ca[(size_t)(b * N_ + tokbase + quad * 4 + r) * C_ + h * 64 + 16 * j + m16] =
            (ushort_t)f2bf(o[j][r]);
  }
}

// ---------------------------------------------------------------------------
// Spatial attention, full-MFMA. Per wave: 16 tokens.
//   S = Q.Ks^T (8 MFMA) -> in-register softmax over p (shfl within 16-lane
//   groups) -> P via LDS f32 round-trip to A-layout -> O = P.Vs^T (8 MFMA).
// Q frags direct from bf16 qkvv; Ks/Vs frags direct from precomputed bf16.
__global__ __launch_bounds__(256) void k_sa_mfma(const ushort_t* __restrict__ qkvv,
                                                 const ushort_t* __restrict__ ksb,
                                                 const ushort_t* __restrict__ vsb,
                                                 ushort_t* __restrict__ x_sa) {
  __shared__ float Pl[64][68];
  const int bh = blockIdx.x;
  const int b = bh >> 2, h = bh & 3;
  const int n0 = blockIdx.y * 64;
  const int lane = threadIdx.x & 63, wave = threadIdx.x >> 6;
  const int m16 = lane & 15, quad = lane >> 4;
  // Q fragment: A[m=token][k=d], d contiguous in qkvv
  const ushort_t* qrow =
      qkvv + (size_t)(b * N_ + n0 + 16 * wave + m16) * OC_ + h * 64 + quad * 8;
  short8 qf0 = *(const short8*)&qrow[0];
  short8 qf1 = *(const short8*)&qrow[32];
  const ushort_t* kb = ksb + (size_t)bh * 4096;
  const ushort_t* vb = vsb + (size_t)bh * 4096;
  short8 kf[2][4], vf[2][4];
#pragma unroll
  for (int ks = 0; ks < 2; ++ks)
#pragma unroll
    for (int j = 0; j < 4; ++j) {
      kf[ks][j] = *(const short8*)&kb[(16 * j + m16) * 64 + ks * 32 + quad * 8];
      vf[ks][j] = *(const short8*)&vb[(16 * j + m16) * 64 + ks * 32 + quad * 8];
    }
  floatx4 s[4];
#pragma unroll
  for (int j = 0; j < 4; ++j) s[j] = (floatx4)(0.f);
#pragma unroll
  for (int j = 0; j < 4; ++j) {
    s[j] = __builtin_amdgcn_mfma_f32_16x16x32_bf16(qf0, kf[0][j], s[j], 0, 0, 0);
    s[j] = __builtin_amdgcn_mfma_f32_16x16x32_bf16(qf1, kf[1][j], s[j], 0, 0, 0);
  }
  // in-register softmax: token = quad*4+r, its 64 p-values live across the
  // 16 lanes sharing this quad (m16) x 4 regs (j).
  float p[4][4];
#pragma unroll
  for (int r = 0; r < 4; ++r) {
    float mr = fmaxf(fmaxf(s[0][r], s[1][r]), fmaxf(s[2][r], s[3][r]));
    mr = fmaxf(mr, __shfl_xor(mr, 1));
    mr = fmaxf(mr, __shfl_xor(mr, 2));
    mr = fmaxf(mr, __shfl_xor(mr, 4));
    mr = fmaxf(mr, __shfl_xor(mr, 8));
    float sr = 0.f;
#pragma unroll
    for (int j = 0; j < 4; ++j) {
      const float e = __expf(s[j][r] - mr);
      p[j][r] = e;
      sr += e;
    }
    sr += __shfl_xor(sr, 1);
    sr += __shfl_xor(sr, 2);
    sr += __shfl_xor(sr, 4);
    sr += __shfl_xor(sr, 8);
    const float inv = 1.f / sr;
#pragma unroll
    for (int j = 0; j < 4; ++j) p[j][r] *= inv;
  }
  // C-layout -> A-layout through LDS (wave-private rows)
#pragma unroll
  for (int j = 0; j < 4; ++j)
#pragma unroll
    for (int r = 0; r < 4; ++r)
      Pl[16 * wave + quad * 4 + r][16 * j + m16] = p[j][r];
  __syncthreads();
  short8 pf[2];
#pragma unroll
  for (int ks = 0; ks < 2; ++ks) {
    float4 x0 = *(const float4*)&Pl[16 * wave + m16][ks * 32 + quad * 8];
    float4 x1 = *(const float4*)&Pl[16 * wave + m16][ks * 32 + quad * 8 + 4];
    short8 v;
    v[0] = f2bf(x0.x); v[1] = f2bf(x0.y); v[2] = f2bf(x0.z); v[3] = f2bf(x0.w);
    v[4] = f2bf(x1.x); v[5] = f2bf(x1.y); v[6] = f2bf(x1.z); v[7] = f2bf(x1.w);
    pf[ks] = v;
  }
  floatx4 o[4];
#pragma unroll
  for (int j = 0; j < 4; ++j) o[j] = (floatx4)(0.f);
#pragma unroll
  for (int j = 0; j < 4; ++j) {
    o[j] = __builtin_amdgcn_mfma_f32_16x16x32_bf16(pf[0], vf[0][j], o[j], 0, 0, 0);
    o[j] = __builtin_amdgcn_mfma_f32_16x16x32_bf16(pf[1], vf[1][j], o[j], 0, 0, 0);
  }
#pragma unroll
  for (int j = 0; j < 4; ++j)
#pragma unroll
    for (int r = 0; r < 4; ++r)
      x_sa[(size_t)(b * N_ + n0 + 16 * wave + quad * 4 + r) * C_ + h * 64 + 16 * j + m16] =
          (ushort_t)f2bf(o[j][r]);
}

// ---------------------------------------------------------------------------
extern "C" void kernel_launch(void* const* d_in, const int* in_sizes, int n_in,
                              void* d_out, int out_size, void* d_ws, size_t ws_size,
                              hipStream_t stream) {
  (void)in_sizes; (void)n_in; (void)out_size; (void)ws_size;
  const float* x  = (const float*)d_in[0];
  // d_in[1] = bank (unused by forward)
  const float* Wq = (const float*)d_in[2];
  const float* WE = (const float*)d_in[3];
  const float* bE = (const float*)d_in[4];
  const float* t1 = (const float*)d_in[5];
  const float* t2 = (const float*)d_in[6];
  const float* W1 = (const float*)d_in[7];
  const float* b1 = (const float*)d_in[8];
  const float* W2 = (const float*)d_in[9];
  const float* b2 = (const float*)d_in[10];
  const float* pa = (const float*)d_in[11];
  float* out = (float*)d_out;

  float* ws = (float*)d_ws;
  size_t off = 0;
  float* Sqk  = ws + off; off += (size_t)B_ * H_ * D_ * D_;      //    131,072
  float* ssq  = ws + off; off += (size_t)B_ * 512;               //      4,096
  float* rn   = ws + off; off += (size_t)B_ * 512;               //      4,096
  float* pp   = ws + off; off += (size_t)NC_SPLIT * PAIR_ELEMS;  //  6,291,456
  ushort_t* qkvv = (ushort_t*)(ws + off); off += (size_t)M_ * OC_ / 2;
  ushort_t* xsa  = (ushort_t*)(ws + off); off += (size_t)M_ * C_ / 2;
  ushort_t* xca  = (ushort_t*)(ws + off); off += (size_t)M_ * C_ / 2;
  ushort_t* ksb  = (ushort_t*)(ws + off); off += 32 * 4096 / 2;  // bf16 [bh][p][d]
  ushort_t* vsb  = (ushort_t*)(ws + off); off += 32 * 4096 / 2;  // bf16 [bh][d][p]
  ushort_t* ab   = (ushort_t*)(ws + off); off += 32 * 4096 / 2;  // bf16 attn [bh][d][e]

  hipMemsetAsync(ssq, 0, 4096 * sizeof(float), stream);

  k_qkvv_mfma<<<dim3(M_ / 128, OC_ / 128), 256, 0, stream>>>(x, Wq, qkvv, ssq);
  k_norms_final<<<16, 256, 0, stream>>>(ssq, rn);
  k_pair_mfma<<<dim3(32, NC_SPLIT), 256, 0, stream>>>(qkvv, WE, pp);
  k_pair_reduce<<<PAIR_ELEMS / 256, 256, 0, stream>>>(pp, bE, rn, t2, Sqk, ksb, vsb);
  k_ca_softmax<<<512, 256, 0, stream>>>(Sqk, rn, t1, ab);
  k_ca_mfma<<<dim3(32, 32), 256, 0, stream>>>(qkvv, ab, xca);
  k_sa_mfma<<<dim3(32, 64), 256, 0, stream>>>(qkvv, ksb, vsb, xsa);
  k_out_mfma<<<dim3(M_ / 128, 2), 256, 0, stream>>>(xsa, xca, W1, b1, W2, b2, pa, out);
}

// Round 7
// 226.552 us; speedup vs baseline: 3.8199x; 1.0438x over previous
//
#include <hip/hip_runtime.h>
#include <cstdint>
#include <cstddef>

// Problem constants (fixed by reference)
constexpr int B_ = 8, N_ = 4096, C_ = 256, H_ = 4, D_ = 64, P_ = 64;
constexpr int OC_ = 4 * C_;      // 1024 qkvv channels
constexpr int M_  = B_ * N_;     // 32768 tokens
constexpr int NC_SPLIT = 16;     // k_pair token splits
constexpr int PAIR_ELEMS = 32 * 3 * 4096;  // per-split partial elements

#define DEV_INLINE __device__ __forceinline__

typedef unsigned short ushort_t;
typedef __attribute__((ext_vector_type(8))) short short8;    // 8 bf16 = 4 VGPR
typedef __attribute__((ext_vector_type(4))) short short4v;   // 4 bf16 = 8 B
typedef __attribute__((ext_vector_type(4))) float floatx4;   // MFMA acc

DEV_INLINE short f2bf(float f) {  // RNE f32 -> bf16
  unsigned int u = __builtin_bit_cast(unsigned int, f);
  u += 0x7FFFu + ((u >> 16) & 1u);
  return (short)(u >> 16);
}

// ---------------------------------------------------------------------------
// One-shot f32 -> bf16 cast of x, W_qkvv, W_out1, W_out2 (memory-bound).
constexpr size_t X4_ = (size_t)M_ * C_ / 4;        // 2,097,152 float4
constexpr size_t WQ4_ = (size_t)OC_ * C_ / 4;      //    65,536
constexpr size_t W14_ = (size_t)128 * C_ / 4;      //     8,192
constexpr size_t TOT4_ = X4_ + WQ4_ + 2 * W14_;

__global__ __launch_bounds__(256) void k_cast(const float* __restrict__ x,
                                              const float* __restrict__ Wq,
                                              const float* __restrict__ W1,
                                              const float* __restrict__ W2,
                                              ushort_t* __restrict__ xb,
                                              ushort_t* __restrict__ wqb,
                                              ushort_t* __restrict__ w1b,
                                              ushort_t* __restrict__ w2b) {
  const size_t stride = (size_t)gridDim.x * 256;
  for (size_t i = blockIdx.x * 256 + threadIdx.x; i < TOT4_; i += stride) {
    const float* src;
    ushort_t* dst;
    size_t o;
    if (i < X4_) { src = x; dst = xb; o = i; }
    else if (i < X4_ + WQ4_) { src = Wq; dst = wqb; o = i - X4_; }
    else if (i < X4_ + WQ4_ + W14_) { src = W1; dst = w1b; o = i - X4_ - WQ4_; }
    else { src = W2; dst = w2b; o = i - X4_ - WQ4_ - W14_; }
    float4 v = ((const float4*)src)[o];
    short4v s = {f2bf(v.x), f2bf(v.y), f2bf(v.z), f2bf(v.w)};
    *(short4v*)&dst[o * 4] = s;
  }
}

// ---------------------------------------------------------------------------
// qkvv = xb @ wqb^T (both bf16) -> bf16 [32768,1024]; fused token-axis
// sum-of-squares for channels 0..511 (q,k) into ssq.
__global__ __launch_bounds__(256) void k_qkvv_mfma(const ushort_t* __restrict__ xb,
                                                   const ushort_t* __restrict__ wqb,
                                                   ushort_t* __restrict__ outb,
                                                   float* __restrict__ ssq) {
  __shared__ __align__(16) short As[128 * 72];
  __shared__ __align__(16) short Bs[128 * 72];
  const int bm = blockIdx.x * 128;
  const int bo = blockIdx.y * 128;
  const int t = threadIdx.x;
  const int oc = t & 7;            // 8-short chunk within 64-wide k
  const int rr = t >> 3;           // row base 0..31
  const int lane = t & 63, wave = t >> 6;
  const int m16 = lane & 15, quad = lane >> 4;
  const int wm = (wave >> 1) << 6, wn = (wave & 1) << 6;
  floatx4 acc[4][4];
#pragma unroll
  for (int i = 0; i < 4; ++i)
#pragma unroll
    for (int j = 0; j < 4; ++j) acc[i][j] = (floatx4)(0.f);
#pragma unroll 1
  for (int k0 = 0; k0 < 256; k0 += 64) {
    short8 a8[4], b8[4];
#pragma unroll
    for (int j = 0; j < 4; ++j) {
      const int r = rr + 32 * j;
      a8[j] = *(const short8*)&xb[(size_t)(bm + r) * 256 + k0 + 8 * oc];
      b8[j] = *(const short8*)&wqb[(size_t)(bo + r) * 256 + k0 + 8 * oc];
    }
    __syncthreads();
#pragma unroll
    for (int j = 0; j < 4; ++j) {
      const int r = rr + 32 * j;
      *(short8*)&As[r * 72 + 8 * oc] = a8[j];
      *(short8*)&Bs[r * 72 + 8 * oc] = b8[j];
    }
    __syncthreads();
#pragma unroll
    for (int ks = 0; ks < 2; ++ks) {
      short8 af[4], bf[4];
#pragma unroll
      for (int i = 0; i < 4; ++i)
        af[i] = *(const short8*)&As[(wm + i * 16 + m16) * 72 + ks * 32 + quad * 8];
#pragma unroll
      for (int j = 0; j < 4; ++j)
        bf[j] = *(const short8*)&Bs[(wn + j * 16 + m16) * 72 + ks * 32 + quad * 8];
#pragma unroll
      for (int i = 0; i < 4; ++i)
#pragma unroll
        for (int j = 0; j < 4; ++j)
          acc[i][j] = __builtin_amdgcn_mfma_f32_16x16x32_bf16(af[i], bf[j], acc[i][j], 0, 0, 0);
    }
  }
#pragma unroll
  for (int i = 0; i < 4; ++i)
#pragma unroll
    for (int r = 0; r < 4; ++r) {
      const int gr = bm + wm + i * 16 + quad * 4 + r;
#pragma unroll
      for (int j = 0; j < 4; ++j)
        outb[(size_t)gr * OC_ + bo + wn + j * 16 + m16] = (ushort_t)f2bf(acc[i][j][r]);
    }
  if (bo < 512) {  // q,k channels: accumulate sum-of-squares over tokens
    const int b = bm >> 12;
    float sj[4];
#pragma unroll
    for (int j = 0; j < 4; ++j) {
      float s = 0.f;
#pragma unroll
      for (int i = 0; i < 4; ++i)
#pragma unroll
        for (int r = 0; r < 4; ++r) s += acc[i][j][r] * acc[i][j][r];
      s += __shfl_xor(s, 16);
      s += __shfl_xor(s, 32);
      sj[j] = s;
    }
    if (lane < 16) {
#pragma unroll
      for (int j = 0; j < 4; ++j)
        atomicAdd(&ssq[b * 512 + bo + wn + 16 * j + m16], sj[j]);
    }
  }
}

// ---------------------------------------------------------------------------
// out[:, half*128 + 0:128] = PReLU(A @ W^T + bias); A, W bf16.
__global__ __launch_bounds__(256) void k_out_mfma(const ushort_t* __restrict__ xsa,
                                                  const ushort_t* __restrict__ xca,
                                                  const ushort_t* __restrict__ w1b,
                                                  const float* __restrict__ b1,
                                                  const ushort_t* __restrict__ w2b,
                                                  const float* __restrict__ b2,
                                                  const float* __restrict__ pa,
                                                  float* __restrict__ out) {
  __shared__ __align__(16) short As[128 * 72];
  __shared__ __align__(16) short Bs[128 * 72];
  const int bm = blockIdx.x * 128;
  const int half = blockIdx.y;
  const ushort_t* A = half ? xca : xsa;
  const ushort_t* W = half ? w2b : w1b;
  const float* bias = half ? b2 : b1;
  const int t = threadIdx.x;
  const int oc = t & 7;
  const int rr = t >> 3;
  const int lane = t & 63, wave = t >> 6;
  const int m16 = lane & 15, quad = lane >> 4;
  const int wm = (wave >> 1) << 6, wn = (wave & 1) << 6;
  floatx4 acc[4][4];
#pragma unroll
  for (int i = 0; i < 4; ++i)
#pragma unroll
    for (int j = 0; j < 4; ++j) acc[i][j] = (floatx4)(0.f);
#pragma unroll 1
  for (int k0 = 0; k0 < 256; k0 += 64) {
    short8 a8[4], b8[4];
#pragma unroll
    for (int j = 0; j < 4; ++j) {
      const int r = rr + 32 * j;
      a8[j] = *(const short8*)&A[(size_t)(bm + r) * 256 + k0 + 8 * oc];
      b8[j] = *(const short8*)&W[(size_t)r * 256 + k0 + 8 * oc];
    }
    __syncthreads();
#pragma unroll
    for (int j = 0; j < 4; ++j) {
      const int r = rr + 32 * j;
      *(short8*)&As[r * 72 + 8 * oc] = a8[j];
      *(short8*)&Bs[r * 72 + 8 * oc] = b8[j];
    }
    __syncthreads();
#pragma unroll
    for (int ks = 0; ks < 2; ++ks) {
      short8 af[4], bf[4];
#pragma unroll
      for (int i = 0; i < 4; ++i)
        af[i] = *(const short8*)&As[(wm + i * 16 + m16) * 72 + ks * 32 + quad * 8];
#pragma unroll
      for (int j = 0; j < 4; ++j)
        bf[j] = *(const short8*)&Bs[(wn + j * 16 + m16) * 72 + ks * 32 + quad * 8];
#pragma unroll
      for (int i = 0; i < 4; ++i)
#pragma unroll
        for (int j = 0; j < 4; ++j)
          acc[i][j] = __builtin_amdgcn_mfma_f32_16x16x32_bf16(af[i], bf[j], acc[i][j], 0, 0, 0);
    }
  }
  const float slope = pa[0];
  float bj[4];
#pragma unroll
  for (int j = 0; j < 4; ++j) bj[j] = bias[wn + j * 16 + m16];
#pragma unroll
  for (int i = 0; i < 4; ++i)
#pragma unroll
    for (int r = 0; r < 4; ++r) {
      const int gr = bm + wm + i * 16 + quad * 4 + r;
#pragma unroll
      for (int j = 0; j < 4; ++j) {
        float v = acc[i][j][r] + bj[j];
        v = v >= 0.f ? v : slope * v;
        out[(size_t)gr * C_ + half * 128 + wn + j * 16 + m16] = v;
      }
    }
}

__global__ void k_norms_final(const float* __restrict__ ssq, float* __restrict__ rn) {
  const int i = blockIdx.x * 256 + threadIdx.x;  // 4096
  rn[i] = 1.f / fmaxf(sqrtf(ssq[i]), 1e-12f);
}

// ---------------------------------------------------------------------------
// Fused per-(b,h) contractions over tokens, MFMA + partial-buffer version.
__global__ __launch_bounds__(256) void k_pair_mfma(const ushort_t* __restrict__ qkvv,
                                                   const float* __restrict__ WE,
                                                   float* __restrict__ pp) {
  __shared__ __align__(16) short Qt[64 * 64];
  __shared__ __align__(16) short Kt[64 * 64];
  __shared__ __align__(16) short Vt[64 * 64];
  __shared__ __align__(16) short Wt[64 * 64];
  const int bh = blockIdx.x;
  const int nc = blockIdx.y;
  const int b = bh >> 2, h = bh & 3;
  const int t = threadIdx.x;
  const int lane = t & 63, wave = t >> 6;
  const int m16 = lane & 15, quad = lane >> 4;
  const int c0 = (t & 15) << 2;    // channel quad for staging
  const int tp = t >> 4;           // 0..15
  floatx4 acc0[4], acc1[4], acc2[4];
#pragma unroll
  for (int j = 0; j < 4; ++j) {
    acc0[j] = (floatx4)(0.f); acc1[j] = (floatx4)(0.f); acc2[j] = (floatx4)(0.f);
  }
  const ushort_t* qb = qkvv + (size_t)b * N_ * OC_;
#pragma unroll 1
  for (int chunk = 0; chunk < 4; ++chunk) {
    const int n0 = nc * 256 + chunk * 64;
    __syncthreads();
#pragma unroll
    for (int j = 0; j < 2; ++j) {
      const int tok0 = 32 * j + 2 * tp;
      const size_t r0 = (size_t)(n0 + tok0) * OC_ + h * 64 + c0;
#pragma unroll
      for (int tt = 0; tt < 3; ++tt) {
        const int off = (tt == 0) ? 0 : (tt == 1 ? 256 : 768);
        short* T = (tt == 0) ? Qt : (tt == 1 ? Kt : Vt);
        short4v a = *(const short4v*)&qb[r0 + off];
        short4v c = *(const short4v*)&qb[r0 + OC_ + off];
#pragma unroll
        for (int i = 0; i < 4; ++i) {
          const int r = c0 + i;
          const int col = tok0 ^ (8 * (r >> 3));
          unsigned int w = (unsigned int)(ushort_t)a[i] |
                           ((unsigned int)(ushort_t)c[i] << 16);
          *(unsigned int*)&T[r * 64 + col] = w;
        }
      }
    }
#pragma unroll
    for (int j2 = 0; j2 < 4; ++j2) {
      const int p = tp + 16 * j2;
      float4 wv = *(const float4*)&WE[(size_t)p * N_ + n0 + c0];
      short4v s = {f2bf(wv.x), f2bf(wv.y), f2bf(wv.z), f2bf(wv.w)};
      *(short4v*)&Wt[p * 64 + (c0 ^ (8 * (p >> 3)))] = s;
    }
    __syncthreads();
#pragma unroll
    for (int ks = 0; ks < 2; ++ks) {
      const int boct = ks * 32 + quad * 8;
      const int rA = 16 * wave + m16;
      const int swA = boct ^ (8 * (rA >> 3));
      short8 af0 = *(const short8*)&Qt[rA * 64 + swA];
      short8 afK = *(const short8*)&Kt[rA * 64 + swA];
      short8 afV = *(const short8*)&Vt[rA * 64 + swA];
      short8 bfK[4], bfW[4];
#pragma unroll
      for (int j = 0; j < 4; ++j) {
        const int rB = 16 * j + m16;
        const int swB = boct ^ (8 * (rB >> 3));
        bfK[j] = *(const short8*)&Kt[rB * 64 + swB];
        bfW[j] = *(const short8*)&Wt[rB * 64 + swB];
      }
#pragma unroll
      for (int j = 0; j < 4; ++j) {
        acc0[j] = __builtin_amdgcn_mfma_f32_16x16x32_bf16(af0, bfK[j], acc0[j], 0, 0, 0);
        acc1[j] = __builtin_amdgcn_mfma_f32_16x16x32_bf16(afK, bfW[j], acc1[j], 0, 0, 0);
        acc2[j] = __builtin_amdgcn_mfma_f32_16x16x32_bf16(afV, bfW[j], acc2[j], 0, 0, 0);
      }
    }
  }
  float* pb = pp + ((size_t)nc * 32 + bh) * (3 * 4096);
#pragma unroll
  for (int j = 0; j < 4; ++j)
#pragma unroll
    for (int r = 0; r < 4; ++r) {
      const int d = 16 * wave + quad * 4 + r;   // row (from A)
      const int cc = 16 * j + m16;              // col (from B)
      pb[0 * 4096 + d * 64 + cc] = acc0[j][r];
      pb[1 * 4096 + cc * 64 + d] = acc1[j][r];  // kp stored [p][d]
      pb[2 * 4096 + d * 64 + cc] = acc2[j][r];  // vp stored [d][p]
    }
}

// Reduce 16 nc-splits and finalize: Sqk f32; ksb = bf16((kp+bE[p])*rn_q[d]*t2);
// vsb = bf16(vp + bE[p]).
__global__ __launch_bounds__(256) void k_pair_reduce(const float* __restrict__ pp,
                                                     const float* __restrict__ bE,
                                                     const float* __restrict__ rn,
                                                     const float* __restrict__ t2,
                                                     float* __restrict__ Sqk,
                                                     ushort_t* __restrict__ ksb,
                                                     ushort_t* __restrict__ vsb) {
  const int e = blockIdx.x * 256 + threadIdx.x;   // < 393216
  float s = 0.f;
#pragma unroll
  for (int nc = 0; nc < NC_SPLIT; ++nc) s += pp[(size_t)nc * PAIR_ELEMS + e];
  const int bh = e / 12288;
  const int rem = e - bh * 12288;
  const int op = rem >> 12;
  const int idx = rem & 4095;
  const int b = bh >> 2, h = bh & 3;
  if (op == 0) {
    Sqk[(size_t)bh * 4096 + idx] = s;
  } else if (op == 1) {
    const int p = idx >> 6, d = idx & 63;
    ksb[(size_t)bh * 4096 + idx] =
        (ushort_t)f2bf((s + bE[p]) * rn[b * 512 + h * 64 + d] * t2[h]);
  } else {
    const int p = idx & 63;
    vsb[(size_t)bh * 4096 + idx] = (ushort_t)f2bf(s + bE[p]);
  }
}

// ---------------------------------------------------------------------------
// Channel-attn softmax -> bf16 attn [bh][d][e].
__global__ __launch_bounds__(256) void k_ca_softmax(const float* __restrict__ Sqk,
                                                    const float* __restrict__ rn,
                                                    const float* __restrict__ temp,
                                                    ushort_t* __restrict__ ab) {
  const int w = threadIdx.x >> 6;
  const int lane = threadIdx.x & 63;
  const int row = blockIdx.x * 4 + w;  // 0..2047 == b*256 + h*64 + dd
  const int b = row >> 8;
  const int rem = row & 255;
  const int h = rem >> 6;
  const float rq = rn[b * 512 + rem];
  const float rk = rn[b * 512 + 256 + h * 64 + lane];
  float l = Sqk[(size_t)row * 64 + lane] * rq * rk * temp[h];
  float m = l;
#pragma unroll
  for (int o = 32; o; o >>= 1) m = fmaxf(m, __shfl_xor(m, o));
  const float e = __expf(l - m);
  float s = e;
#pragma unroll
  for (int o = 32; o; o >>= 1) s += __shfl_xor(s, o);
  ab[(size_t)row * 64 + lane] = (ushort_t)f2bf(e / s);
}

// ---------------------------------------------------------------------------
// x_ca = attn @ v_ca per (b,h): MFMA, all fragments direct global 16B loads.
__global__ __launch_bounds__(256) void k_ca_mfma(const ushort_t* __restrict__ qkvv,
                                                 const ushort_t* __restrict__ ab,
                                                 ushort_t* __restrict__ x_ca) {
  const int bh = blockIdx.x;
  const int b = bh >> 2, h = bh & 3;
  const int n0 = blockIdx.y * 128;
  const int lane = threadIdx.x & 63, wave = threadIdx.x >> 6;
  const int m16 = lane & 15, quad = lane >> 4;
  const ushort_t* abb = ab + (size_t)bh * 4096;
  short8 bf[2][4];
#pragma unroll
  for (int ks = 0; ks < 2; ++ks)
#pragma unroll
    for (int j = 0; j < 4; ++j)
      bf[ks][j] = *(const short8*)&abb[(16 * j + m16) * 64 + ks * 32 + quad * 8];
#pragma unroll
  for (int mm = 0; mm < 2; ++mm) {
    const int tokbase = n0 + 64 * mm + 16 * wave;
    const ushort_t* vrow =
        qkvv + (size_t)(b * N_ + tokbase + m16) * OC_ + 512 + h * 64 + quad * 8;
    short8 af0 = *(const short8*)&vrow[0];
    short8 af1 = *(const short8*)&vrow[32];
    floatx4 o[4];
#pragma unroll
    for (int j = 0; j < 4; ++j) o[j] = (floatx4)(0.f);
#pragma unroll
    for (int j = 0; j < 4; ++j) {
      o[j] = __builtin_amdgcn_mfma_f32_16x16x32_bf16(af0, bf[0][j], o[j], 0, 0, 0);
      o[j] = __builtin_amdgcn_mfma_f32_16x16x32_bf16(af1, bf[1][j], o[j], 0, 0, 0);
    }
#pragma unroll
    for (int j = 0; j < 4; ++j)
#pragma unroll
      for (int r = 0; r < 4; ++r)
        x_ca[(size_t)(b * N_ + tokbase + quad * 4 + r) * C_ + h * 64 + 16 * j + m16] =
            (ushort_t)f2bf(o[j][r]);
  }
}

// ---------------------------------------------------------------------------
// Spatial attention, full-MFMA. Per wave: 16 tokens.
__global__ __launch_bounds__(256) void k_sa_mfma(const ushort_t* __restrict__ qkvv,
                                                 const ushort_t* __restrict__ ksb,
                                                 const ushort_t* __restrict__ vsb,
                                                 ushort_t* __restrict__ x_sa) {
  __shared__ float Pl[64][68];
  const int bh = blockIdx.x;
  const int b = bh >> 2, h = bh & 3;
  const int n0 = blockIdx.y * 64;
  const int lane = threadIdx.x & 63, wave = threadIdx.x >> 6;
  const int m16 = lane & 15, quad = lane >> 4;
  const ushort_t* qrow =
      qkvv + (size_t)(b * N_ + n0 + 16 * wave + m16) * OC_ + h * 64 + quad * 8;
  short8 qf0 = *(const short8*)&qrow[0];
  short8 qf1 = *(const short8*)&qrow[32];
  const ushort_t* kb = ksb + (size_t)bh * 4096;
  const ushort_t* vb = vsb + (size_t)bh * 4096;
  short8 kf[2][4], vf[2][4];
#pragma unroll
  for (int ks = 0; ks < 2; ++ks)
#pragma unroll
    for (int j = 0; j < 4; ++j) {
      kf[ks][j] = *(const short8*)&kb[(16 * j + m16) * 64 + ks * 32 + quad * 8];
      vf[ks][j] = *(const short8*)&vb[(16 * j + m16) * 64 + ks * 32 + quad * 8];
    }
  floatx4 s[4];
#pragma unroll
  for (int j = 0; j < 4; ++j) s[j] = (floatx4)(0.f);
#pragma unroll
  for (int j = 0; j < 4; ++j) {
    s[j] = __builtin_amdgcn_mfma_f32_16x16x32_bf16(qf0, kf[0][j], s[j], 0, 0, 0);
    s[j] = __builtin_amdgcn_mfma_f32_16x16x32_bf16(qf1, kf[1][j], s[j], 0, 0, 0);
  }
  float p[4][4];
#pragma unroll
  for (int r = 0; r < 4; ++r) {
    float mr = fmaxf(fmaxf(s[0][r], s[1][r]), fmaxf(s[2][r], s[3][r]));
    mr = fmaxf(mr, __shfl_xor(mr, 1));
    mr = fmaxf(mr, __shfl_xor(mr, 2));
    mr = fmaxf(mr, __shfl_xor(mr, 4));
    mr = fmaxf(mr, __shfl_xor(mr, 8));
    float sr = 0.f;
#pragma unroll
    for (int j = 0; j < 4; ++j) {
      const float e = __expf(s[j][r] - mr);
      p[j][r] = e;
      sr += e;
    }
    sr += __shfl_xor(sr, 1);
    sr += __shfl_xor(sr, 2);
    sr += __shfl_xor(sr, 4);
    sr += __shfl_xor(sr, 8);
    const float inv = 1.f / sr;
#pragma unroll
    for (int j = 0; j < 4; ++j) p[j][r] *= inv;
  }
#pragma unroll
  for (int j = 0; j < 4; ++j)
#pragma unroll
    for (int r = 0; r < 4; ++r)
      Pl[16 * wave + quad * 4 + r][16 * j + m16] = p[j][r];
  __syncthreads();
  short8 pf[2];
#pragma unroll
  for (int ks = 0; ks < 2; ++ks) {
    float4 x0 = *(const float4*)&Pl[16 * wave + m16][ks * 32 + quad * 8];
    float4 x1 = *(const float4*)&Pl[16 * wave + m16][ks * 32 + quad * 8 + 4];
    short8 v;
    v[0] = f2bf(x0.x); v[1] = f2bf(x0.y); v[2] = f2bf(x0.z); v[3] = f2bf(x0.w);
    v[4] = f2bf(x1.x); v[5] = f2bf(x1.y); v[6] = f2bf(x1.z); v[7] = f2bf(x1.w);
    pf[ks] = v;
  }
  floatx4 o[4];
#pragma unroll
  for (int j = 0; j < 4; ++j) o[j] = (floatx4)(0.f);
#pragma unroll
  for (int j = 0; j < 4; ++j) {
    o[j] = __builtin_amdgcn_mfma_f32_16x16x32_bf16(pf[0], vf[0][j], o[j], 0, 0, 0);
    o[j] = __builtin_amdgcn_mfma_f32_16x16x32_bf16(pf[1], vf[1][j], o[j], 0, 0, 0);
  }
#pragma unroll
  for (int j = 0; j < 4; ++j)
#pragma unroll
    for (int r = 0; r < 4; ++r)
      x_sa[(size_t)(b * N_ + n0 + 16 * wave + quad * 4 + r) * C_ + h * 64 + 16 * j + m16] =
          (ushort_t)f2bf(o[j][r]);
}

// ---------------------------------------------------------------------------
extern "C" void kernel_launch(void* const* d_in, const int* in_sizes, int n_in,
                              void* d_out, int out_size, void* d_ws, size_t ws_size,
                              hipStream_t stream) {
  (void)in_sizes; (void)n_in; (void)out_size; (void)ws_size;
  const float* x  = (const float*)d_in[0];
  // d_in[1] = bank (unused by forward)
  const float* Wq = (const float*)d_in[2];
  const float* WE = (const float*)d_in[3];
  const float* bE = (const float*)d_in[4];
  const float* t1 = (const float*)d_in[5];
  const float* t2 = (const float*)d_in[6];
  const float* W1 = (const float*)d_in[7];
  const float* b1 = (const float*)d_in[8];
  const float* W2 = (const float*)d_in[9];
  const float* b2 = (const float*)d_in[10];
  const float* pa = (const float*)d_in[11];
  float* out = (float*)d_out;

  float* ws = (float*)d_ws;
  size_t off = 0;
  float* Sqk  = ws + off; off += (size_t)B_ * H_ * D_ * D_;      //    131,072
  float* ssq  = ws + off; off += (size_t)B_ * 512;               //      4,096
  float* rn   = ws + off; off += (size_t)B_ * 512;               //      4,096
  float* pp   = ws + off; off += (size_t)NC_SPLIT * PAIR_ELEMS;  //  6,291,456
  ushort_t* qkvv = (ushort_t*)(ws + off); off += (size_t)M_ * OC_ / 2;
  ushort_t* xsa  = (ushort_t*)(ws + off); off += (size_t)M_ * C_ / 2;
  ushort_t* xca  = (ushort_t*)(ws + off); off += (size_t)M_ * C_ / 2;
  ushort_t* ksb  = (ushort_t*)(ws + off); off += 32 * 4096 / 2;  // bf16 [bh][p][d]
  ushort_t* vsb  = (ushort_t*)(ws + off); off += 32 * 4096 / 2;  // bf16 [bh][d][p]
  ushort_t* ab   = (ushort_t*)(ws + off); off += 32 * 4096 / 2;  // bf16 attn
  ushort_t* xb   = (ushort_t*)(ws + off); off += (size_t)M_ * C_ / 2;   // bf16 x
  ushort_t* wqb  = (ushort_t*)(ws + off); off += (size_t)OC_ * C_ / 2;  // bf16 Wq
  ushort_t* w1b  = (ushort_t*)(ws + off); off += (size_t)128 * C_ / 2;
  ushort_t* w2b  = (ushort_t*)(ws + off); off += (size_t)128 * C_ / 2;

  hipMemsetAsync(ssq, 0, 4096 * sizeof(float), stream);

  k_cast<<<2048, 256, 0, stream>>>(x, Wq, W1, W2, xb, wqb, w1b, w2b);
  k_qkvv_mfma<<<dim3(M_ / 128, OC_ / 128), 256, 0, stream>>>(xb, wqb, qkvv, ssq);
  k_norms_final<<<16, 256, 0, stream>>>(ssq, rn);
  k_pair_mfma<<<dim3(32, NC_SPLIT), 256, 0, stream>>>(qkvv, WE, pp);
  k_pair_reduce<<<PAIR_ELEMS / 256, 256, 0, stream>>>(pp, bE, rn, t2, Sqk, ksb, vsb);
  k_ca_softmax<<<512, 256, 0, stream>>>(Sqk, rn, t1, ab);
  k_ca_mfma<<<dim3(32, 32), 256, 0, stream>>>(qkvv, ab, xca);
  k_sa_mfma<<<dim3(32, 64), 256, 0, stream>>>(qkvv, ksb, vsb, xsa);
  k_out_mfma<<<dim3(M_ / 128, 2), 256, 0, stream>>>(xsa, xca, w1b, b1, w2b, b2, pa, out);
}